// Round 1
// baseline (2574.611 us; speedup 1.0000x reference)
//
#include <hip/hip_runtime.h>
#include <math.h>

// ---------------- problem constants ----------------
constexpr int NN = 50000;   // nodes
constexpr int EE = 800000;  // edges
constexpr int DD = 128;     // feature dim (= O)

// ---------------- workspace layout (float offsets) ----------------
// weights
constexpr int OFF_WT_NODE  = 0;                    // [128][512] k-major: cols 0:asrc+asub 1:adst-asub 2:pool 3:pool2
constexpr int OFF_WT_AMUL  = 65536;                // [128][128]
constexpr int OFF_WT_FINAL = 81920;                // [384][128] rows: 0-127 neigh, 128-255 neigh2, 256-383 self
constexpr int OFF_WT_MLP   = 131072;               // 2 x [128][128]
constexpr int OFF_WAOUT    = 163840;               // [128]
constexpr int OFF_BE       = 163968;               // [128] b_asrc+b_adst+b_asub+b_amul
constexpr int OFF_BFIN     = 164096;               // [128] b_self+b_neigh+b_neigh2
constexpr int OFF_BAOUT    = 164224;               // [1] (padded)
// big arrays
constexpr int OFF_CNODE    = 164240;               // [N][512]: 0:S_src 128:S_dst 256:h 384:h2
constexpr int OFF_E        = OFF_CNODE + NN*512;   // [E]
constexpr int OFF_NEIGH    = OFF_E + EE;           // [N][128]
constexpr int OFF_NEIGH2   = OFF_NEIGH + NN*128;   // [N][128]
constexpr int OFF_CNT      = OFF_NEIGH2 + NN*128;  // [N]

// ---------------- device helpers ----------------
__device__ __forceinline__ float gelu_f(float x) {
    return 0.5f * x * (1.0f + erff(x * 0.70710678118654752440f));
}
__device__ __forceinline__ float leaky_f(float x) {
    return x > 0.0f ? x : 0.2f * x;
}
__device__ __forceinline__ void atomicMaxFloat(float* addr, float v) {
    int iv = __float_as_int(v);
    if (iv >= 0) atomicMax((int*)addr, iv);
    else         atomicMin((unsigned int*)addr, (unsigned int)iv);
}
__device__ __forceinline__ float block_sum128(float v, float* sbuf) {
    #pragma unroll
    for (int o = 32; o > 0; o >>= 1) v += __shfl_down(v, o, 64);
    int lane = threadIdx.x & 63, w = threadIdx.x >> 6;
    if (lane == 0) sbuf[w] = v;
    __syncthreads();
    float r = sbuf[0] + sbuf[1];
    __syncthreads();
    return r;
}

// ---------------- weight normalization ----------------
struct WnormArgs {
    const float *asrc_v, *asrc_g, *asrc_b;
    const float *adst_v, *adst_g, *adst_b;
    const float *asub_v, *asub_g, *asub_b;
    const float *amul_v, *amul_g, *amul_b;
    const float *aout_v, *aout_g, *aout_b;
    const float *pool_v, *pool_g, *pool_b;
    const float *pool2_v, *pool2_g, *pool2_b;
    const float *self_v, *self_g, *self_b;
    const float *neigh_v, *neigh_g, *neigh_b;
    const float *neigh2_v, *neigh2_g, *neigh2_b;
    const float *mlp_v, *mlp_g, *mlp_b;
    float* ws;
};

__global__ __launch_bounds__(128) void wnorm_kernel(WnormArgs a) {
    __shared__ float sbuf[2];
    int bid = blockIdx.x, i = threadIdx.x;
    float* ws = a.ws;
    if (bid < 1280) {
        int o = bid & 127, grp = bid >> 7;
        const float *v1 = nullptr, *g1 = nullptr, *v2 = nullptr, *g2 = nullptr;
        float sgn2 = 1.0f; float* dst = nullptr; int stride = 0;
        switch (grp) {
            case 0: v1=a.asrc_v; g1=a.asrc_g; v2=a.asub_v; g2=a.asub_g; sgn2= 1.f; dst=ws+OFF_WT_NODE+o;        stride=512; break;
            case 1: v1=a.adst_v; g1=a.adst_g; v2=a.asub_v; g2=a.asub_g; sgn2=-1.f; dst=ws+OFF_WT_NODE+128+o;    stride=512; break;
            case 2: v1=a.pool_v;  g1=a.pool_g;  dst=ws+OFF_WT_NODE+256+o;          stride=512; break;
            case 3: v1=a.pool2_v; g1=a.pool2_g; dst=ws+OFF_WT_NODE+384+o;          stride=512; break;
            case 4: v1=a.amul_v;  g1=a.amul_g;  dst=ws+OFF_WT_AMUL+o;              stride=128; break;
            case 5: v1=a.neigh_v; g1=a.neigh_g; dst=ws+OFF_WT_FINAL+o;             stride=128; break;
            case 6: v1=a.neigh2_v;g1=a.neigh2_g;dst=ws+OFF_WT_FINAL+128*128+o;     stride=128; break;
            case 7: v1=a.self_v;  g1=a.self_g;  dst=ws+OFF_WT_FINAL+256*128+o;     stride=128; break;
            case 8: v1=a.mlp_v;        g1=a.mlp_g;     dst=ws+OFF_WT_MLP+o;        stride=128; break;
            case 9: v1=a.mlp_v+16384;  g1=a.mlp_g+128; dst=ws+OFF_WT_MLP+16384+o;  stride=128; break;
        }
        float x1 = v1[o*128 + i];
        float n1 = sqrtf(block_sum128(x1*x1, sbuf));
        float w = g1[o] * x1 / n1;
        if (v2) {
            float x2 = v2[o*128 + i];
            float n2 = sqrtf(block_sum128(x2*x2, sbuf));
            w += sgn2 * g2[o] * x2 / n2;
        }
        dst[i * stride] = w;
    } else {
        // aout row + bias vectors
        float v = a.aout_v[i];
        float n = sqrtf(block_sum128(v*v, sbuf));
        ws[OFF_WAOUT + i] = a.aout_g[0] * v / n;
        ws[OFF_BE + i]    = a.asrc_b[i] + a.adst_b[i] + a.asub_b[i] + a.amul_b[i];
        ws[OFF_BFIN + i]  = a.self_b[i] + a.neigh_b[i] + a.neigh2_b[i];
        if (i == 0) ws[OFF_BAOUT] = a.aout_b[0];
    }
}

// ---------------- GEMM tile geometry: BM=64, BN=128, BK=32, 256 threads, 4x8/thread ----------------
// As: [64][36] (row-major, pad 36 -> float4-aligned rows). Bs: [32][132] (k-major, pad 132).

// node GEMM: C_node[N][512] = feat[N][128] @ WT_node[128][512]; gelu+bias on col groups 2,3
__global__ __launch_bounds__(256) void gemm_node(const float* __restrict__ feat,
                                                 const float* __restrict__ pool_b,
                                                 const float* __restrict__ pool2_b,
                                                 float* __restrict__ ws) {
    __shared__ float As[64 * 36];
    __shared__ float Bs[32 * 132];
    const float* WT = ws + OFF_WT_NODE;
    float* C = ws + OFF_CNODE;
    int tid = threadIdx.x, tx = tid & 15, ty = tid >> 4;
    int row0 = blockIdx.x * 64;
    int gy = blockIdx.y, n0 = gy * 128;
    float acc[4][8] = {};
    for (int k0 = 0; k0 < 128; k0 += 32) {
        #pragma unroll
        for (int it = 0; it < 2; ++it) {
            int idx = tid + it * 256;
            int r = idx >> 3, kq = idx & 7;
            int rr = min(row0 + r, NN - 1);
            float4 v = ((const float4*)feat)[rr * 32 + (k0 >> 2) + kq];
            ((float4*)As)[r * 9 + kq] = v;
        }
        #pragma unroll
        for (int it = 0; it < 4; ++it) {
            int idx = tid + it * 256;
            int kk = idx >> 5, cq = idx & 31;
            float4 v = ((const float4*)WT)[(k0 + kk) * 128 + (n0 >> 2) + cq];
            ((float4*)Bs)[kk * 33 + cq] = v;
        }
        __syncthreads();
        #pragma unroll 4
        for (int kk = 0; kk < 32; ++kk) {
            float4 b0 = ((const float4*)Bs)[kk * 33 + tx];
            float4 b1 = ((const float4*)Bs)[kk * 33 + 16 + tx];
            #pragma unroll
            for (int j = 0; j < 4; ++j) {
                float av = As[(ty * 4 + j) * 36 + kk];
                acc[j][0] += av * b0.x; acc[j][1] += av * b0.y;
                acc[j][2] += av * b0.z; acc[j][3] += av * b0.w;
                acc[j][4] += av * b1.x; acc[j][5] += av * b1.y;
                acc[j][6] += av * b1.z; acc[j][7] += av * b1.w;
            }
        }
        __syncthreads();
    }
    #pragma unroll
    for (int j = 0; j < 4; ++j) {
        int row = row0 + ty * 4 + j;
        if (row >= NN) continue;
        #pragma unroll
        for (int g = 0; g < 2; ++g) {
            int c = g * 64 + tx * 4;
            float4 v = make_float4(acc[j][g*4+0], acc[j][g*4+1], acc[j][g*4+2], acc[j][g*4+3]);
            if (gy == 2) {
                v.x = gelu_f(v.x + pool_b[c+0]); v.y = gelu_f(v.y + pool_b[c+1]);
                v.z = gelu_f(v.z + pool_b[c+2]); v.w = gelu_f(v.w + pool_b[c+3]);
            } else if (gy == 3) {
                v.x = gelu_f(v.x + pool2_b[c+0]); v.y = gelu_f(v.y + pool2_b[c+1]);
                v.z = gelu_f(v.z + pool2_b[c+2]); v.w = gelu_f(v.w + pool2_b[c+3]);
            }
            ((float4*)C)[(row * 512 + n0 + c) >> 2] = v;
        }
    }
}

// edge GEMM: pre[64][128] = (fs*fd)@WT_amul + S_src[src] + S_dst[dst] + b_e; e = leaky(gelu(pre)@w_aout + b_aout)
__global__ __launch_bounds__(256) void gemm_edge(const float* __restrict__ feat,
                                                 const int* __restrict__ src,
                                                 const int* __restrict__ dst,
                                                 float* __restrict__ ws) {
    __shared__ float As[64 * 36];
    __shared__ float Bs[32 * 132];
    __shared__ int sI[64], dI[64];
    __shared__ float waout_s[128], be_s[128];
    int tid = threadIdx.x, tx = tid & 15, ty = tid >> 4;
    int e0 = blockIdx.x * 64;
    if (tid < 64) { sI[tid] = src[e0 + tid]; dI[tid] = dst[e0 + tid]; }
    else if (tid < 192) { int i = tid - 64; waout_s[i] = ws[OFF_WAOUT + i]; be_s[i] = ws[OFF_BE + i]; }
    float b_aout = ws[OFF_BAOUT];
    const float* WT = ws + OFF_WT_AMUL;
    const float* Cn = ws + OFF_CNODE;
    float* e_out = ws + OFF_E;
    __syncthreads();
    float acc[4][8] = {};
    for (int k0 = 0; k0 < 128; k0 += 32) {
        #pragma unroll
        for (int it = 0; it < 2; ++it) {
            int idx = tid + it * 256;
            int r = idx >> 3, kq = idx & 7;
            int s = sI[r], d = dI[r];
            float4 va = ((const float4*)feat)[s * 32 + (k0 >> 2) + kq];
            float4 vb = ((const float4*)feat)[d * 32 + (k0 >> 2) + kq];
            float4 m; m.x = va.x * vb.x; m.y = va.y * vb.y; m.z = va.z * vb.z; m.w = va.w * vb.w;
            ((float4*)As)[r * 9 + kq] = m;
        }
        #pragma unroll
        for (int it = 0; it < 4; ++it) {
            int idx = tid + it * 256;
            int kk = idx >> 5, cq = idx & 31;
            float4 v = ((const float4*)WT)[(k0 + kk) * 32 + cq];
            ((float4*)Bs)[kk * 33 + cq] = v;
        }
        __syncthreads();
        #pragma unroll 4
        for (int kk = 0; kk < 32; ++kk) {
            float4 b0 = ((const float4*)Bs)[kk * 33 + tx];
            float4 b1 = ((const float4*)Bs)[kk * 33 + 16 + tx];
            #pragma unroll
            for (int j = 0; j < 4; ++j) {
                float av = As[(ty * 4 + j) * 36 + kk];
                acc[j][0] += av * b0.x; acc[j][1] += av * b0.y;
                acc[j][2] += av * b0.z; acc[j][3] += av * b0.w;
                acc[j][4] += av * b1.x; acc[j][5] += av * b1.y;
                acc[j][6] += av * b1.z; acc[j][7] += av * b1.w;
            }
        }
        __syncthreads();
    }
    // fused epilogue: add gathered node terms, gelu, dot with w_aout, reduce over 16 tx lanes
    #pragma unroll
    for (int j = 0; j < 4; ++j) {
        int r = ty * 4 + j;
        int s = sI[r], d = dI[r];
        float partial = 0.0f;
        #pragma unroll
        for (int g = 0; g < 2; ++g) {
            int c = g * 64 + tx * 4;
            float4 ss = ((const float4*)Cn)[(s * 512 + c) >> 2];
            float4 sd = ((const float4*)Cn)[(d * 512 + 128 + c) >> 2];
            float4 be = *(const float4*)&be_s[c];
            float4 wa = *(const float4*)&waout_s[c];
            float v0 = gelu_f(acc[j][g*4+0] + ss.x + sd.x + be.x);
            float v1 = gelu_f(acc[j][g*4+1] + ss.y + sd.y + be.y);
            float v2 = gelu_f(acc[j][g*4+2] + ss.z + sd.z + be.z);
            float v3 = gelu_f(acc[j][g*4+3] + ss.w + sd.w + be.w);
            partial += v0 * wa.x + v1 * wa.y + v2 * wa.z + v3 * wa.w;
        }
        #pragma unroll
        for (int m = 8; m >= 1; m >>= 1) partial += __shfl_xor(partial, m, 16);
        if (tx == 0) e_out[e0 + r] = leaky_f(partial + b_aout);
    }
}

// init aggregation buffers
__global__ __launch_bounds__(256) void init_kernel(float* __restrict__ ws) {
    int i = blockIdx.x * 256 + threadIdx.x;
    if (i < NN * 128) {
        ws[OFF_NEIGH + i]  = -INFINITY;
        ws[OFF_NEIGH2 + i] = 0.0f;
    }
    if (i < NN) ws[OFF_CNT + i] = 0.0f;
}

// scatter: per-edge atomics into neigh (max), neigh2 (sum), cnt
__global__ __launch_bounds__(256) void scatter_kernel(const int* __restrict__ src,
                                                      const int* __restrict__ dst,
                                                      float* __restrict__ ws) {
    int edge = blockIdx.x * 4 + (threadIdx.x >> 6);
    int lane = threadIdx.x & 63;
    const float* Cn = ws + OFF_CNODE;
    const float* e_arr = ws + OFF_E;
    float* neigh  = ws + OFF_NEIGH;
    float* neigh2 = ws + OFF_NEIGH2;
    float* cnt    = ws + OFF_CNT;
    float ev = e_arr[edge];
    int s = src[edge], d = dst[edge];
    float2 h  = *(const float2*)&Cn[s * 512 + 256 + lane * 2];
    float2 h2 = *(const float2*)&Cn[s * 512 + 384 + lane * 2];
    atomicMaxFloat(&neigh[d * 128 + lane * 2 + 0], ev * h.x);
    atomicMaxFloat(&neigh[d * 128 + lane * 2 + 1], ev * h.y);
    atomicAdd(&neigh2[d * 128 + lane * 2 + 0], ev * h2.x);
    atomicAdd(&neigh2[d * 128 + lane * 2 + 1], ev * h2.y);
    if (lane == 0) atomicAdd(&cnt[d], 1.0f);
}

// final GEMM: rst[N][128] = [neigh', neigh2', feat] @ WT_final + b_final
__global__ __launch_bounds__(256) void gemm_final(const float* __restrict__ feat,
                                                  float* __restrict__ out,
                                                  float* __restrict__ ws) {
    __shared__ float As[64 * 36];
    __shared__ float Bs[32 * 132];
    int tid = threadIdx.x, tx = tid & 15, ty = tid >> 4;
    int row0 = blockIdx.x * 64;
    const float* WT = ws + OFF_WT_FINAL;
    const float* neigh  = ws + OFF_NEIGH;
    const float* neigh2 = ws + OFF_NEIGH2;
    const float* cnt    = ws + OFF_CNT;
    const float* bfin   = ws + OFF_BFIN;
    float acc[4][8] = {};
    for (int k0 = 0; k0 < 384; k0 += 32) {
        #pragma unroll
        for (int it = 0; it < 2; ++it) {
            int idx = tid + it * 256;
            int r = idx >> 3, kq = idx & 7;
            int rr = min(row0 + r, NN - 1);
            int kg = k0 + kq * 4;
            float4 v;
            if (k0 < 128) {
                float c = cnt[rr];
                float4 nv = ((const float4*)neigh)[rr * 32 + (kg >> 2)];
                if (c > 0.0f) v = nv; else v = make_float4(0, 0, 0, 0);
            } else if (k0 < 256) {
                float ic = 1.0f / fmaxf(cnt[rr], 1.0f);
                float4 nv = ((const float4*)neigh2)[rr * 32 + ((kg - 128) >> 2)];
                v = make_float4(nv.x * ic, nv.y * ic, nv.z * ic, nv.w * ic);
            } else {
                v = ((const float4*)feat)[rr * 32 + ((kg - 256) >> 2)];
            }
            ((float4*)As)[r * 9 + kq] = v;
        }
        #pragma unroll
        for (int it = 0; it < 4; ++it) {
            int idx = tid + it * 256;
            int kk = idx >> 5, cq = idx & 31;
            float4 v = ((const float4*)WT)[(k0 + kk) * 32 + cq];
            ((float4*)Bs)[kk * 33 + cq] = v;
        }
        __syncthreads();
        #pragma unroll 4
        for (int kk = 0; kk < 32; ++kk) {
            float4 b0 = ((const float4*)Bs)[kk * 33 + tx];
            float4 b1 = ((const float4*)Bs)[kk * 33 + 16 + tx];
            #pragma unroll
            for (int j = 0; j < 4; ++j) {
                float av = As[(ty * 4 + j) * 36 + kk];
                acc[j][0] += av * b0.x; acc[j][1] += av * b0.y;
                acc[j][2] += av * b0.z; acc[j][3] += av * b0.w;
                acc[j][4] += av * b1.x; acc[j][5] += av * b1.y;
                acc[j][6] += av * b1.z; acc[j][7] += av * b1.w;
            }
        }
        __syncthreads();
    }
    #pragma unroll
    for (int j = 0; j < 4; ++j) {
        int row = row0 + ty * 4 + j;
        if (row >= NN) continue;
        #pragma unroll
        for (int g = 0; g < 2; ++g) {
            int c = g * 64 + tx * 4;
            float4 v = make_float4(acc[j][g*4+0] + bfin[c+0], acc[j][g*4+1] + bfin[c+1],
                                   acc[j][g*4+2] + bfin[c+2], acc[j][g*4+3] + bfin[c+3]);
            ((float4*)out)[(row * 128 + c) >> 2] = v;
        }
    }
}

// MLP layer: out[r][c] = rst_in[r][c] + gelu(rst_in[r][:]) @ WT_mlp[l] + mlp_b[l]
__global__ __launch_bounds__(256) void gemm_mlp(const float* __restrict__ rst_in,
                                                float* __restrict__ out,
                                                const float* __restrict__ mlp_b,
                                                int layer,
                                                float* __restrict__ ws) {
    __shared__ float As[64 * 36];
    __shared__ float Bs[32 * 132];
    int tid = threadIdx.x, tx = tid & 15, ty = tid >> 4;
    int row0 = blockIdx.x * 64;
    const float* WT = ws + OFF_WT_MLP + layer * 16384;
    const float* bias = mlp_b + layer * 128;
    float acc[4][8] = {};
    for (int k0 = 0; k0 < 128; k0 += 32) {
        #pragma unroll
        for (int it = 0; it < 2; ++it) {
            int idx = tid + it * 256;
            int r = idx >> 3, kq = idx & 7;
            int rr = min(row0 + r, NN - 1);
            float4 v = ((const float4*)rst_in)[rr * 32 + (k0 >> 2) + kq];
            v.x = gelu_f(v.x); v.y = gelu_f(v.y); v.z = gelu_f(v.z); v.w = gelu_f(v.w);
            ((float4*)As)[r * 9 + kq] = v;
        }
        #pragma unroll
        for (int it = 0; it < 4; ++it) {
            int idx = tid + it * 256;
            int kk = idx >> 5, cq = idx & 31;
            float4 v = ((const float4*)WT)[(k0 + kk) * 32 + cq];
            ((float4*)Bs)[kk * 33 + cq] = v;
        }
        __syncthreads();
        #pragma unroll 4
        for (int kk = 0; kk < 32; ++kk) {
            float4 b0 = ((const float4*)Bs)[kk * 33 + tx];
            float4 b1 = ((const float4*)Bs)[kk * 33 + 16 + tx];
            #pragma unroll
            for (int j = 0; j < 4; ++j) {
                float av = As[(ty * 4 + j) * 36 + kk];
                acc[j][0] += av * b0.x; acc[j][1] += av * b0.y;
                acc[j][2] += av * b0.z; acc[j][3] += av * b0.w;
                acc[j][4] += av * b1.x; acc[j][5] += av * b1.y;
                acc[j][6] += av * b1.z; acc[j][7] += av * b1.w;
            }
        }
        __syncthreads();
    }
    #pragma unroll
    for (int j = 0; j < 4; ++j) {
        int row = row0 + ty * 4 + j;
        if (row >= NN) continue;
        #pragma unroll
        for (int g = 0; g < 2; ++g) {
            int c = g * 64 + tx * 4;
            float4 old = ((const float4*)rst_in)[(row * 128 + c) >> 2];
            float4 v = make_float4(old.x + acc[j][g*4+0] + bias[c+0],
                                   old.y + acc[j][g*4+1] + bias[c+1],
                                   old.z + acc[j][g*4+2] + bias[c+2],
                                   old.w + acc[j][g*4+3] + bias[c+3]);
            ((float4*)out)[(row * 128 + c) >> 2] = v;
        }
    }
}

// ---------------- host launch ----------------
extern "C" void kernel_launch(void* const* d_in, const int* in_sizes, int n_in,
                              void* d_out, int out_size, void* d_ws, size_t ws_size,
                              hipStream_t stream) {
    const float* feat = (const float*)d_in[0];
    WnormArgs wa;
    wa.asrc_v = (const float*)d_in[1];  wa.asrc_g = (const float*)d_in[2];  wa.asrc_b = (const float*)d_in[3];
    wa.adst_v = (const float*)d_in[4];  wa.adst_g = (const float*)d_in[5];  wa.adst_b = (const float*)d_in[6];
    wa.asub_v = (const float*)d_in[7];  wa.asub_g = (const float*)d_in[8];  wa.asub_b = (const float*)d_in[9];
    wa.amul_v = (const float*)d_in[10]; wa.amul_g = (const float*)d_in[11]; wa.amul_b = (const float*)d_in[12];
    wa.aout_v = (const float*)d_in[13]; wa.aout_g = (const float*)d_in[14]; wa.aout_b = (const float*)d_in[15];
    wa.pool_v = (const float*)d_in[16]; wa.pool_g = (const float*)d_in[17]; wa.pool_b = (const float*)d_in[18];
    wa.pool2_v= (const float*)d_in[19]; wa.pool2_g= (const float*)d_in[20]; wa.pool2_b= (const float*)d_in[21];
    wa.self_v = (const float*)d_in[22]; wa.self_g = (const float*)d_in[23]; wa.self_b = (const float*)d_in[24];
    wa.neigh_v= (const float*)d_in[25]; wa.neigh_g= (const float*)d_in[26]; wa.neigh_b= (const float*)d_in[27];
    wa.neigh2_v=(const float*)d_in[28]; wa.neigh2_g=(const float*)d_in[29]; wa.neigh2_b=(const float*)d_in[30];
    wa.mlp_v  = (const float*)d_in[31]; wa.mlp_g  = (const float*)d_in[32]; wa.mlp_b  = (const float*)d_in[33];
    const int* src = (const int*)d_in[34];
    const int* dst = (const int*)d_in[35];
    float* out = (float*)d_out;
    float* ws = (float*)d_ws;
    wa.ws = ws;

    // 1) normalized weights + fused bias vectors
    wnorm_kernel<<<dim3(1281), dim3(128), 0, stream>>>(wa);
    // 2) node-level GEMM: S_src, S_dst, h, h2
    gemm_node<<<dim3(782, 4), dim3(256), 0, stream>>>(feat, wa.pool_b, wa.pool2_b, ws);
    // 3) init aggregation buffers
    init_kernel<<<dim3((NN * 128 + 255) / 256), dim3(256), 0, stream>>>(ws);
    // 4) edge GEMM + fused attention epilogue -> e[E]
    gemm_edge<<<dim3(EE / 64), dim3(256), 0, stream>>>(feat, src, dst, ws);
    // 5) scatter aggregation (max / sum / count)
    scatter_kernel<<<dim3(EE / 4), dim3(256), 0, stream>>>(src, dst, ws);
    // 6) final fused GEMM -> rst (d_out)
    gemm_final<<<dim3(782), dim3(256), 0, stream>>>(feat, out, ws);
    // 7) two residual MLP layers (in-place, row-wise safe)
    gemm_mlp<<<dim3(782), dim3(256), 0, stream>>>(out, out, wa.mlp_b, 0, ws);
    gemm_mlp<<<dim3(782), dim3(256), 0, stream>>>(out, out, wa.mlp_b, 1, ws);
}

// Round 2
// 1155.764 us; speedup vs baseline: 2.2276x; 2.2276x over previous
//
#include <hip/hip_runtime.h>
#include <math.h>

// ---------------- problem constants ----------------
constexpr int NN = 50000;   // nodes
constexpr int EE = 800000;  // edges

// ---------------- workspace layout (float offsets) ----------------
// weights
constexpr int OFF_WT_NODE  = 0;                    // [128][512] k-major: cols 0:asrc+asub 1:adst-asub 2:pool 3:pool2
constexpr int OFF_WT_AMUL  = 65536;                // [128][128]
constexpr int OFF_WT_FINAL = 81920;                // [384][128] rows: 0-127 neigh, 128-255 neigh2, 256-383 self
constexpr int OFF_WT_MLP   = 131072;               // 2 x [128][128]
constexpr int OFF_WAOUT    = 163840;               // [128]
constexpr int OFF_BE       = 163968;               // [128] b_asrc+b_adst+b_asub+b_amul
constexpr int OFF_BFIN     = 164096;               // [128] b_self+b_neigh+b_neigh2
constexpr int OFF_BAOUT    = 164224;               // [1] (padded)
// big arrays
constexpr int OFF_CNODE    = 164240;               // [N][512]: 0:S_src 128:S_dst 256:h 384:h2
constexpr int OFF_E        = OFF_CNODE + NN*512;   // [E]
constexpr int OFF_NEIGH    = OFF_E + EE;           // [N][128] (post-processed: zeroed where cnt==0)
constexpr int OFF_NEIGH2   = OFF_NEIGH + NN*128;   // [N][128] (post-processed: mean already applied)
// CSR sort scratch
constexpr int OFF_HIST     = OFF_NEIGH2 + NN*128;  // [N] int
constexpr int OFF_STARTS   = OFF_HIST + NN;        // [N+1] int
constexpr int OFF_CURSOR   = OFF_STARTS + NN + 8;  // [N] int
constexpr int OFF_SSRC     = OFF_CURSOR + NN;      // [E] int  (src sorted by dst)
constexpr int OFF_SEV      = OFF_SSRC + EE;        // [E] float (e sorted by dst)

// ---------------- device helpers ----------------
__device__ __forceinline__ float gelu_f(float x) {
    return 0.5f * x * (1.0f + erff(x * 0.70710678118654752440f));
}
__device__ __forceinline__ float leaky_f(float x) {
    return x > 0.0f ? x : 0.2f * x;
}
__device__ __forceinline__ float block_sum128(float v, float* sbuf) {
    #pragma unroll
    for (int o = 32; o > 0; o >>= 1) v += __shfl_down(v, o, 64);
    int lane = threadIdx.x & 63, w = threadIdx.x >> 6;
    if (lane == 0) sbuf[w] = v;
    __syncthreads();
    float r = sbuf[0] + sbuf[1];
    __syncthreads();
    return r;
}

// ---------------- weight normalization ----------------
struct WnormArgs {
    const float *asrc_v, *asrc_g, *asrc_b;
    const float *adst_v, *adst_g, *adst_b;
    const float *asub_v, *asub_g, *asub_b;
    const float *amul_v, *amul_g, *amul_b;
    const float *aout_v, *aout_g, *aout_b;
    const float *pool_v, *pool_g, *pool_b;
    const float *pool2_v, *pool2_g, *pool2_b;
    const float *self_v, *self_g, *self_b;
    const float *neigh_v, *neigh_g, *neigh_b;
    const float *neigh2_v, *neigh2_g, *neigh2_b;
    const float *mlp_v, *mlp_g, *mlp_b;
    float* ws;
};

__global__ __launch_bounds__(128) void wnorm_kernel(WnormArgs a) {
    __shared__ float sbuf[2];
    int bid = blockIdx.x, i = threadIdx.x;
    float* ws = a.ws;
    if (bid < 1280) {
        int o = bid & 127, grp = bid >> 7;
        const float *v1 = nullptr, *g1 = nullptr, *v2 = nullptr, *g2 = nullptr;
        float sgn2 = 1.0f; float* dst = nullptr; int stride = 0;
        switch (grp) {
            case 0: v1=a.asrc_v; g1=a.asrc_g; v2=a.asub_v; g2=a.asub_g; sgn2= 1.f; dst=ws+OFF_WT_NODE+o;        stride=512; break;
            case 1: v1=a.adst_v; g1=a.adst_g; v2=a.asub_v; g2=a.asub_g; sgn2=-1.f; dst=ws+OFF_WT_NODE+128+o;    stride=512; break;
            case 2: v1=a.pool_v;  g1=a.pool_g;  dst=ws+OFF_WT_NODE+256+o;          stride=512; break;
            case 3: v1=a.pool2_v; g1=a.pool2_g; dst=ws+OFF_WT_NODE+384+o;          stride=512; break;
            case 4: v1=a.amul_v;  g1=a.amul_g;  dst=ws+OFF_WT_AMUL+o;              stride=128; break;
            case 5: v1=a.neigh_v; g1=a.neigh_g; dst=ws+OFF_WT_FINAL+o;             stride=128; break;
            case 6: v1=a.neigh2_v;g1=a.neigh2_g;dst=ws+OFF_WT_FINAL+128*128+o;     stride=128; break;
            case 7: v1=a.self_v;  g1=a.self_g;  dst=ws+OFF_WT_FINAL+256*128+o;     stride=128; break;
            case 8: v1=a.mlp_v;        g1=a.mlp_g;     dst=ws+OFF_WT_MLP+o;        stride=128; break;
            case 9: v1=a.mlp_v+16384;  g1=a.mlp_g+128; dst=ws+OFF_WT_MLP+16384+o;  stride=128; break;
        }
        float x1 = v1[o*128 + i];
        float n1 = sqrtf(block_sum128(x1*x1, sbuf));
        float w = g1[o] * x1 / n1;
        if (v2) {
            float x2 = v2[o*128 + i];
            float n2 = sqrtf(block_sum128(x2*x2, sbuf));
            w += sgn2 * g2[o] * x2 / n2;
        }
        dst[i * stride] = w;
    } else {
        float v = a.aout_v[i];
        float n = sqrtf(block_sum128(v*v, sbuf));
        ws[OFF_WAOUT + i] = a.aout_g[0] * v / n;
        ws[OFF_BE + i]    = a.asrc_b[i] + a.adst_b[i] + a.asub_b[i] + a.amul_b[i];
        ws[OFF_BFIN + i]  = a.self_b[i] + a.neigh_b[i] + a.neigh2_b[i];
        if (i == 0) ws[OFF_BAOUT] = a.aout_b[0];
    }
}

// ---------------- CSR-by-dst construction ----------------
__global__ __launch_bounds__(256) void hist_zero_kernel(float* __restrict__ ws) {
    int i = blockIdx.x * 256 + threadIdx.x;
    if (i < NN) ((int*)(ws + OFF_HIST))[i] = 0;
}

__global__ __launch_bounds__(256) void hist_kernel(const int* __restrict__ dst, float* __restrict__ ws) {
    int e = blockIdx.x * 256 + threadIdx.x;
    if (e < EE) atomicAdd(&((int*)(ws + OFF_HIST))[dst[e]], 1);
}

__global__ __launch_bounds__(1024) void scan_kernel(float* __restrict__ ws) {
    __shared__ int sp[1024];
    const int* hist = (const int*)(ws + OFF_HIST);
    int* starts = (int*)(ws + OFF_STARTS);
    int* cursor = (int*)(ws + OFF_CURSOR);
    int t = threadIdx.x;
    const int C = 49;  // 1024*49 >= 50000
    int base = t * C;
    int local = 0;
    for (int j = 0; j < C; ++j) { int idx = base + j; if (idx < NN) local += hist[idx]; }
    sp[t] = local;
    __syncthreads();
    for (int o = 1; o < 1024; o <<= 1) {
        int v = (t >= o) ? sp[t - o] : 0;
        __syncthreads();
        sp[t] += v;
        __syncthreads();
    }
    int run = sp[t] - local;  // exclusive prefix
    for (int j = 0; j < C; ++j) {
        int idx = base + j;
        if (idx < NN) { starts[idx] = run; cursor[idx] = run; run += hist[idx]; }
    }
    if (t == 0) starts[NN] = EE;
}

__global__ __launch_bounds__(256) void scatteridx_kernel(const int* __restrict__ src,
                                                         const int* __restrict__ dst,
                                                         float* __restrict__ ws) {
    int e = blockIdx.x * 256 + threadIdx.x;
    if (e >= EE) return;
    int d = dst[e];
    int pos = atomicAdd(&((int*)(ws + OFF_CURSOR))[d], 1);
    ((int*)(ws + OFF_SSRC))[pos] = src[e];
    ws[OFF_SEV + pos] = ws[OFF_E + e];
}

// ---------------- segmented reduction: one wave per dst node ----------------
__global__ __launch_bounds__(256) void segreduce_kernel(float* __restrict__ ws) {
    int n = blockIdx.x * 4 + (threadIdx.x >> 6);
    int lane = threadIdx.x & 63;
    const int* starts = (const int*)(ws + OFF_STARTS);
    const int* ssrc = (const int*)(ws + OFF_SSRC);
    const float* sev = ws + OFF_SEV;
    const float* Cn = ws + OFF_CNODE;
    int s0 = starts[n], s1 = starts[n + 1];
    float2 mx = make_float2(-INFINITY, -INFINITY);
    float2 sm = make_float2(0.f, 0.f);
    for (int i = s0; i < s1; ++i) {
        int s = ssrc[i];
        float ev = sev[i];
        float2 h  = *(const float2*)&Cn[s * 512 + 256 + lane * 2];
        float2 h2 = *(const float2*)&Cn[s * 512 + 384 + lane * 2];
        mx.x = fmaxf(mx.x, ev * h.x);  mx.y = fmaxf(mx.y, ev * h.y);
        sm.x += ev * h2.x;             sm.y += ev * h2.y;
    }
    int cnt = s1 - s0;
    if (cnt == 0) { mx.x = 0.f; mx.y = 0.f; }
    float ic = 1.0f / (float)max(cnt, 1);
    *(float2*)&ws[OFF_NEIGH  + n * 128 + lane * 2] = mx;
    *(float2*)&ws[OFF_NEIGH2 + n * 128 + lane * 2] = make_float2(sm.x * ic, sm.y * ic);
}

// ---------------- GEMM tile geometry: BM=64, BN=128, BK=32, 256 threads, 4x8/thread ----------------

// node GEMM: C_node[N][512] = feat[N][128] @ WT_node[128][512]; gelu+bias on col groups 2,3
__global__ __launch_bounds__(256) void gemm_node(const float* __restrict__ feat,
                                                 const float* __restrict__ pool_b,
                                                 const float* __restrict__ pool2_b,
                                                 float* __restrict__ ws) {
    __shared__ float As[64 * 36];
    __shared__ float Bs[32 * 132];
    const float* WT = ws + OFF_WT_NODE;
    float* C = ws + OFF_CNODE;
    int tid = threadIdx.x, tx = tid & 15, ty = tid >> 4;
    int row0 = blockIdx.x * 64;
    int gy = blockIdx.y, n0 = gy * 128;
    float acc[4][8] = {};
    for (int k0 = 0; k0 < 128; k0 += 32) {
        #pragma unroll
        for (int it = 0; it < 2; ++it) {
            int idx = tid + it * 256;
            int r = idx >> 3, kq = idx & 7;
            int rr = min(row0 + r, NN - 1);
            float4 v = ((const float4*)feat)[rr * 32 + (k0 >> 2) + kq];
            ((float4*)As)[r * 9 + kq] = v;
        }
        #pragma unroll
        for (int it = 0; it < 4; ++it) {
            int idx = tid + it * 256;
            int kk = idx >> 5, cq = idx & 31;
            float4 v = ((const float4*)WT)[(k0 + kk) * 128 + (n0 >> 2) + cq];
            ((float4*)Bs)[kk * 33 + cq] = v;
        }
        __syncthreads();
        #pragma unroll 4
        for (int kk = 0; kk < 32; ++kk) {
            float4 b0 = ((const float4*)Bs)[kk * 33 + tx];
            float4 b1 = ((const float4*)Bs)[kk * 33 + 16 + tx];
            #pragma unroll
            for (int j = 0; j < 4; ++j) {
                float av = As[(ty * 4 + j) * 36 + kk];
                acc[j][0] += av * b0.x; acc[j][1] += av * b0.y;
                acc[j][2] += av * b0.z; acc[j][3] += av * b0.w;
                acc[j][4] += av * b1.x; acc[j][5] += av * b1.y;
                acc[j][6] += av * b1.z; acc[j][7] += av * b1.w;
            }
        }
        __syncthreads();
    }
    #pragma unroll
    for (int j = 0; j < 4; ++j) {
        int row = row0 + ty * 4 + j;
        if (row >= NN) continue;
        #pragma unroll
        for (int g = 0; g < 2; ++g) {
            int c = g * 64 + tx * 4;
            float4 v = make_float4(acc[j][g*4+0], acc[j][g*4+1], acc[j][g*4+2], acc[j][g*4+3]);
            if (gy == 2) {
                v.x = gelu_f(v.x + pool_b[c+0]); v.y = gelu_f(v.y + pool_b[c+1]);
                v.z = gelu_f(v.z + pool_b[c+2]); v.w = gelu_f(v.w + pool_b[c+3]);
            } else if (gy == 3) {
                v.x = gelu_f(v.x + pool2_b[c+0]); v.y = gelu_f(v.y + pool2_b[c+1]);
                v.z = gelu_f(v.z + pool2_b[c+2]); v.w = gelu_f(v.w + pool2_b[c+3]);
            }
            ((float4*)C)[(row * 512 + n0 + c) >> 2] = v;
        }
    }
}

// edge GEMM: pre[64][128] = (fs*fd)@WT_amul + S_src[src] + S_dst[dst] + b_e; e = leaky(gelu(pre)@w_aout + b_aout)
__global__ __launch_bounds__(256) void gemm_edge(const float* __restrict__ feat,
                                                 const int* __restrict__ src,
                                                 const int* __restrict__ dst,
                                                 float* __restrict__ ws) {
    __shared__ float As[64 * 36];
    __shared__ float Bs[32 * 132];
    __shared__ int sI[64], dI[64];
    __shared__ float waout_s[128], be_s[128];
    int tid = threadIdx.x, tx = tid & 15, ty = tid >> 4;
    int e0 = blockIdx.x * 64;
    if (tid < 64) { sI[tid] = src[e0 + tid]; dI[tid] = dst[e0 + tid]; }
    else if (tid < 192) { int i = tid - 64; waout_s[i] = ws[OFF_WAOUT + i]; be_s[i] = ws[OFF_BE + i]; }
    float b_aout = ws[OFF_BAOUT];
    const float* WT = ws + OFF_WT_AMUL;
    const float* Cn = ws + OFF_CNODE;
    float* e_out = ws + OFF_E;
    __syncthreads();
    float acc[4][8] = {};
    for (int k0 = 0; k0 < 128; k0 += 32) {
        #pragma unroll
        for (int it = 0; it < 2; ++it) {
            int idx = tid + it * 256;
            int r = idx >> 3, kq = idx & 7;
            int s = sI[r], d = dI[r];
            float4 va = ((const float4*)feat)[s * 32 + (k0 >> 2) + kq];
            float4 vb = ((const float4*)feat)[d * 32 + (k0 >> 2) + kq];
            float4 m; m.x = va.x * vb.x; m.y = va.y * vb.y; m.z = va.z * vb.z; m.w = va.w * vb.w;
            ((float4*)As)[r * 9 + kq] = m;
        }
        #pragma unroll
        for (int it = 0; it < 4; ++it) {
            int idx = tid + it * 256;
            int kk = idx >> 5, cq = idx & 31;
            float4 v = ((const float4*)WT)[(k0 + kk) * 32 + cq];
            ((float4*)Bs)[kk * 33 + cq] = v;
        }
        __syncthreads();
        #pragma unroll 4
        for (int kk = 0; kk < 32; ++kk) {
            float4 b0 = ((const float4*)Bs)[kk * 33 + tx];
            float4 b1 = ((const float4*)Bs)[kk * 33 + 16 + tx];
            #pragma unroll
            for (int j = 0; j < 4; ++j) {
                float av = As[(ty * 4 + j) * 36 + kk];
                acc[j][0] += av * b0.x; acc[j][1] += av * b0.y;
                acc[j][2] += av * b0.z; acc[j][3] += av * b0.w;
                acc[j][4] += av * b1.x; acc[j][5] += av * b1.y;
                acc[j][6] += av * b1.z; acc[j][7] += av * b1.w;
            }
        }
        __syncthreads();
    }
    #pragma unroll
    for (int j = 0; j < 4; ++j) {
        int r = ty * 4 + j;
        int s = sI[r], d = dI[r];
        float partial = 0.0f;
        #pragma unroll
        for (int g = 0; g < 2; ++g) {
            int c = g * 64 + tx * 4;
            float4 ss = ((const float4*)Cn)[(s * 512 + c) >> 2];
            float4 sd = ((const float4*)Cn)[(d * 512 + 128 + c) >> 2];
            float4 be = *(const float4*)&be_s[c];
            float4 wa = *(const float4*)&waout_s[c];
            float v0 = gelu_f(acc[j][g*4+0] + ss.x + sd.x + be.x);
            float v1 = gelu_f(acc[j][g*4+1] + ss.y + sd.y + be.y);
            float v2 = gelu_f(acc[j][g*4+2] + ss.z + sd.z + be.z);
            float v3 = gelu_f(acc[j][g*4+3] + ss.w + sd.w + be.w);
            partial += v0 * wa.x + v1 * wa.y + v2 * wa.z + v3 * wa.w;
        }
        #pragma unroll
        for (int m = 8; m >= 1; m >>= 1) partial += __shfl_xor(partial, m, 16);
        if (tx == 0) e_out[e0 + r] = leaky_f(partial + b_aout);
    }
}

// final GEMM: rst[N][128] = [neigh, neigh2, feat] @ WT_final + b_final  (neigh/neigh2 already post-processed)
__global__ __launch_bounds__(256) void gemm_final(const float* __restrict__ feat,
                                                  float* __restrict__ out,
                                                  float* __restrict__ ws) {
    __shared__ float As[64 * 36];
    __shared__ float Bs[32 * 132];
    int tid = threadIdx.x, tx = tid & 15, ty = tid >> 4;
    int row0 = blockIdx.x * 64;
    const float* WT = ws + OFF_WT_FINAL;
    const float* neigh  = ws + OFF_NEIGH;
    const float* neigh2 = ws + OFF_NEIGH2;
    const float* bfin   = ws + OFF_BFIN;
    float acc[4][8] = {};
    for (int k0 = 0; k0 < 384; k0 += 32) {
        #pragma unroll
        for (int it = 0; it < 2; ++it) {
            int idx = tid + it * 256;
            int r = idx >> 3, kq = idx & 7;
            int rr = min(row0 + r, NN - 1);
            int kg = k0 + kq * 4;
            float4 v;
            if (k0 < 128) {
                v = ((const float4*)neigh)[rr * 32 + (kg >> 2)];
            } else if (k0 < 256) {
                v = ((const float4*)neigh2)[rr * 32 + ((kg - 128) >> 2)];
            } else {
                v = ((const float4*)feat)[rr * 32 + ((kg - 256) >> 2)];
            }
            ((float4*)As)[r * 9 + kq] = v;
        }
        #pragma unroll
        for (int it = 0; it < 4; ++it) {
            int idx = tid + it * 256;
            int kk = idx >> 5, cq = idx & 31;
            float4 v = ((const float4*)WT)[(k0 + kk) * 32 + cq];
            ((float4*)Bs)[kk * 33 + cq] = v;
        }
        __syncthreads();
        #pragma unroll 4
        for (int kk = 0; kk < 32; ++kk) {
            float4 b0 = ((const float4*)Bs)[kk * 33 + tx];
            float4 b1 = ((const float4*)Bs)[kk * 33 + 16 + tx];
            #pragma unroll
            for (int j = 0; j < 4; ++j) {
                float av = As[(ty * 4 + j) * 36 + kk];
                acc[j][0] += av * b0.x; acc[j][1] += av * b0.y;
                acc[j][2] += av * b0.z; acc[j][3] += av * b0.w;
                acc[j][4] += av * b1.x; acc[j][5] += av * b1.y;
                acc[j][6] += av * b1.z; acc[j][7] += av * b1.w;
            }
        }
        __syncthreads();
    }
    #pragma unroll
    for (int j = 0; j < 4; ++j) {
        int row = row0 + ty * 4 + j;
        if (row >= NN) continue;
        #pragma unroll
        for (int g = 0; g < 2; ++g) {
            int c = g * 64 + tx * 4;
            float4 v = make_float4(acc[j][g*4+0] + bfin[c+0], acc[j][g*4+1] + bfin[c+1],
                                   acc[j][g*4+2] + bfin[c+2], acc[j][g*4+3] + bfin[c+3]);
            ((float4*)out)[(row * 128 + c) >> 2] = v;
        }
    }
}

// MLP layer: out[r][c] = rst_in[r][c] + gelu(rst_in[r][:]) @ WT_mlp[l] + mlp_b[l]
__global__ __launch_bounds__(256) void gemm_mlp(const float* __restrict__ rst_in,
                                                float* __restrict__ out,
                                                const float* __restrict__ mlp_b,
                                                int layer,
                                                float* __restrict__ ws) {
    __shared__ float As[64 * 36];
    __shared__ float Bs[32 * 132];
    int tid = threadIdx.x, tx = tid & 15, ty = tid >> 4;
    int row0 = blockIdx.x * 64;
    const float* WT = ws + OFF_WT_MLP + layer * 16384;
    const float* bias = mlp_b + layer * 128;
    float acc[4][8] = {};
    for (int k0 = 0; k0 < 128; k0 += 32) {
        #pragma unroll
        for (int it = 0; it < 2; ++it) {
            int idx = tid + it * 256;
            int r = idx >> 3, kq = idx & 7;
            int rr = min(row0 + r, NN - 1);
            float4 v = ((const float4*)rst_in)[rr * 32 + (k0 >> 2) + kq];
            v.x = gelu_f(v.x); v.y = gelu_f(v.y); v.z = gelu_f(v.z); v.w = gelu_f(v.w);
            ((float4*)As)[r * 9 + kq] = v;
        }
        #pragma unroll
        for (int it = 0; it < 4; ++it) {
            int idx = tid + it * 256;
            int kk = idx >> 5, cq = idx & 31;
            float4 v = ((const float4*)WT)[(k0 + kk) * 32 + cq];
            ((float4*)Bs)[kk * 33 + cq] = v;
        }
        __syncthreads();
        #pragma unroll 4
        for (int kk = 0; kk < 32; ++kk) {
            float4 b0 = ((const float4*)Bs)[kk * 33 + tx];
            float4 b1 = ((const float4*)Bs)[kk * 33 + 16 + tx];
            #pragma unroll
            for (int j = 0; j < 4; ++j) {
                float av = As[(ty * 4 + j) * 36 + kk];
                acc[j][0] += av * b0.x; acc[j][1] += av * b0.y;
                acc[j][2] += av * b0.z; acc[j][3] += av * b0.w;
                acc[j][4] += av * b1.x; acc[j][5] += av * b1.y;
                acc[j][6] += av * b1.z; acc[j][7] += av * b1.w;
            }
        }
        __syncthreads();
    }
    #pragma unroll
    for (int j = 0; j < 4; ++j) {
        int row = row0 + ty * 4 + j;
        if (row >= NN) continue;
        #pragma unroll
        for (int g = 0; g < 2; ++g) {
            int c = g * 64 + tx * 4;
            float4 old = ((const float4*)rst_in)[(row * 128 + c) >> 2];
            float4 v = make_float4(old.x + acc[j][g*4+0] + bias[c+0],
                                   old.y + acc[j][g*4+1] + bias[c+1],
                                   old.z + acc[j][g*4+2] + bias[c+2],
                                   old.w + acc[j][g*4+3] + bias[c+3]);
            ((float4*)out)[(row * 128 + c) >> 2] = v;
        }
    }
}

// ---------------- host launch ----------------
extern "C" void kernel_launch(void* const* d_in, const int* in_sizes, int n_in,
                              void* d_out, int out_size, void* d_ws, size_t ws_size,
                              hipStream_t stream) {
    const float* feat = (const float*)d_in[0];
    WnormArgs wa;
    wa.asrc_v = (const float*)d_in[1];  wa.asrc_g = (const float*)d_in[2];  wa.asrc_b = (const float*)d_in[3];
    wa.adst_v = (const float*)d_in[4];  wa.adst_g = (const float*)d_in[5];  wa.adst_b = (const float*)d_in[6];
    wa.asub_v = (const float*)d_in[7];  wa.asub_g = (const float*)d_in[8];  wa.asub_b = (const float*)d_in[9];
    wa.amul_v = (const float*)d_in[10]; wa.amul_g = (const float*)d_in[11]; wa.amul_b = (const float*)d_in[12];
    wa.aout_v = (const float*)d_in[13]; wa.aout_g = (const float*)d_in[14]; wa.aout_b = (const float*)d_in[15];
    wa.pool_v = (const float*)d_in[16]; wa.pool_g = (const float*)d_in[17]; wa.pool_b = (const float*)d_in[18];
    wa.pool2_v= (const float*)d_in[19]; wa.pool2_g= (const float*)d_in[20]; wa.pool2_b= (const float*)d_in[21];
    wa.self_v = (const float*)d_in[22]; wa.self_g = (const float*)d_in[23]; wa.self_b = (const float*)d_in[24];
    wa.neigh_v= (const float*)d_in[25]; wa.neigh_g= (const float*)d_in[26]; wa.neigh_b= (const float*)d_in[27];
    wa.neigh2_v=(const float*)d_in[28]; wa.neigh2_g=(const float*)d_in[29]; wa.neigh2_b=(const float*)d_in[30];
    wa.mlp_v  = (const float*)d_in[31]; wa.mlp_g  = (const float*)d_in[32]; wa.mlp_b  = (const float*)d_in[33];
    const int* src = (const int*)d_in[34];
    const int* dst = (const int*)d_in[35];
    float* out = (float*)d_out;
    float* ws = (float*)d_ws;
    wa.ws = ws;

    // 1) normalized weights + fused bias vectors
    wnorm_kernel<<<dim3(1281), dim3(128), 0, stream>>>(wa);
    // 2) CSR-by-dst: histogram + scan (independent of e, run early)
    hist_zero_kernel<<<dim3((NN + 255) / 256), dim3(256), 0, stream>>>(ws);
    hist_kernel<<<dim3((EE + 255) / 256), dim3(256), 0, stream>>>(dst, ws);
    scan_kernel<<<dim3(1), dim3(1024), 0, stream>>>(ws);
    // 3) node-level GEMM: S_src, S_dst, h, h2
    gemm_node<<<dim3(782, 4), dim3(256), 0, stream>>>(feat, wa.pool_b, wa.pool2_b, ws);
    // 4) edge GEMM + fused attention epilogue -> e[E]
    gemm_edge<<<dim3(EE / 64), dim3(256), 0, stream>>>(feat, src, dst, ws);
    // 5) sort edges by dst (src + e payloads)
    scatteridx_kernel<<<dim3((EE + 255) / 256), dim3(256), 0, stream>>>(src, dst, ws);
    // 6) segmented reduce: one wave per dst node -> neigh (max, zeroed), neigh2 (mean)
    segreduce_kernel<<<dim3(NN / 4), dim3(256), 0, stream>>>(ws);
    // 7) final fused GEMM -> rst (d_out)
    gemm_final<<<dim3(782), dim3(256), 0, stream>>>(feat, out, ws);
    // 8) two residual MLP layers (in-place, row-wise safe)
    gemm_mlp<<<dim3(782), dim3(256), 0, stream>>>(out, out, wa.mlp_b, 0, ws);
    gemm_mlp<<<dim3(782), dim3(256), 0, stream>>>(out, out, wa.mlp_b, 1, ws);
}

// Round 3
// 1076.287 us; speedup vs baseline: 2.3921x; 1.0738x over previous
//
#include <hip/hip_runtime.h>
#include <math.h>

// ---------------- problem constants ----------------
constexpr int NN = 50000;   // nodes
constexpr int EE = 800000;  // edges

// ---------------- workspace layout (float offsets) ----------------
constexpr int OFF_WT_NODE  = 0;                    // [128][512] k-major: cols 0:asrc+asub 1:adst-asub 2:pool 3:pool2
constexpr int OFF_WT_AMUL  = 65536;                // [128][128] k-major f32
constexpr int OFF_WT_FINAL = 81920;                // [384][128] rows: 0-127 neigh, 128-255 neigh2, 256-383 self
constexpr int OFF_WT_MLP   = 131072;               // 2 x [128][128]
constexpr int OFF_WAOUT    = 163840;               // [128]
constexpr int OFF_BE       = 163968;               // [128] b_asrc+b_adst+b_asub+b_amul
constexpr int OFF_BFIN     = 164096;               // [128] b_self+b_neigh+b_neigh2
constexpr int OFF_BAOUT    = 164224;               // [1] (padded)
// big arrays
constexpr int OFF_CNODE    = 164240;               // [N][512]: cols 256:h 384:h2 (cols 0-255 unused now)
constexpr int OFF_E        = OFF_CNODE + NN*512;   // [E]
constexpr int OFF_NEIGH    = OFF_E + EE;           // [N][128] final neigh (segreduce output)
constexpr int OFF_NEIGH2   = OFF_NEIGH + NN*128;   // [N][128] final neigh2 (segreduce output)
// CSR sort scratch
constexpr int OFF_HIST     = OFF_NEIGH2 + NN*128;  // [N] int
constexpr int OFF_STARTS   = OFF_HIST + NN;        // [N+1] int
constexpr int OFF_CURSOR   = OFF_STARTS + NN + 8;  // [N] int
constexpr int OFF_SSRC     = OFF_CURSOR + NN;      // [E] int  (src sorted by dst)
constexpr int OFF_SEV      = OFF_SSRC + EE;        // [E] float (e sorted by dst)
// bf16 aliases (regions only written AFTER gemm_edge completes):
//   featbf : N*128 bf16  = 3.2M float-slots  -> aliases OFF_NEIGH
//   wtbf   : 128*128 bf16 (amul^T [o][k])    -> aliases OFF_NEIGH + 3300000
//   sbf    : N*256 bf16 (S_src|S_dst)        -> aliases OFF_NEIGH2 (exactly fills it)

typedef __attribute__((ext_vector_type(8))) short bf16x8;
typedef __attribute__((ext_vector_type(4))) float f32x4;

// ---------------- device helpers ----------------
__device__ __forceinline__ float gelu_f(float x) {
    return 0.5f * x * (1.0f + erff(x * 0.70710678118654752440f));
}
__device__ __forceinline__ float leaky_f(float x) {
    return x > 0.0f ? x : 0.2f * x;
}
__device__ __forceinline__ unsigned short f2bf(float x) {
    unsigned u = __float_as_uint(x);
    return (unsigned short)((u + 0x7fffu + ((u >> 16) & 1u)) >> 16);
}
__device__ __forceinline__ float bf2f(unsigned short b) {
    return __uint_as_float(((unsigned)b) << 16);
}
__device__ __forceinline__ unsigned mulpack(unsigned a, unsigned b) {
    float a0 = __uint_as_float(a << 16), a1 = __uint_as_float(a & 0xffff0000u);
    float b0 = __uint_as_float(b << 16), b1 = __uint_as_float(b & 0xffff0000u);
    return (unsigned)f2bf(a0 * b0) | ((unsigned)f2bf(a1 * b1) << 16);
}
__device__ __forceinline__ float block_sum128(float v, float* sbuf) {
    #pragma unroll
    for (int o = 32; o > 0; o >>= 1) v += __shfl_down(v, o, 64);
    int lane = threadIdx.x & 63, w = threadIdx.x >> 6;
    if (lane == 0) sbuf[w] = v;
    __syncthreads();
    float r = sbuf[0] + sbuf[1];
    __syncthreads();
    return r;
}

// ---------------- weight normalization ----------------
struct WnormArgs {
    const float *asrc_v, *asrc_g, *asrc_b;
    const float *adst_v, *adst_g, *adst_b;
    const float *asub_v, *asub_g, *asub_b;
    const float *amul_v, *amul_g, *amul_b;
    const float *aout_v, *aout_g, *aout_b;
    const float *pool_v, *pool_g, *pool_b;
    const float *pool2_v, *pool2_g, *pool2_b;
    const float *self_v, *self_g, *self_b;
    const float *neigh_v, *neigh_g, *neigh_b;
    const float *neigh2_v, *neigh2_g, *neigh2_b;
    const float *mlp_v, *mlp_g, *mlp_b;
    float* ws;
};

__global__ __launch_bounds__(128) void wnorm_kernel(WnormArgs a) {
    __shared__ float sbuf[2];
    int bid = blockIdx.x, i = threadIdx.x;
    float* ws = a.ws;
    if (bid < 1280) {
        int o = bid & 127, grp = bid >> 7;
        const float *v1 = nullptr, *g1 = nullptr, *v2 = nullptr, *g2 = nullptr;
        float sgn2 = 1.0f; float* dst = nullptr; int stride = 0;
        switch (grp) {
            case 0: v1=a.asrc_v; g1=a.asrc_g; v2=a.asub_v; g2=a.asub_g; sgn2= 1.f; dst=ws+OFF_WT_NODE+o;        stride=512; break;
            case 1: v1=a.adst_v; g1=a.adst_g; v2=a.asub_v; g2=a.asub_g; sgn2=-1.f; dst=ws+OFF_WT_NODE+128+o;    stride=512; break;
            case 2: v1=a.pool_v;  g1=a.pool_g;  dst=ws+OFF_WT_NODE+256+o;          stride=512; break;
            case 3: v1=a.pool2_v; g1=a.pool2_g; dst=ws+OFF_WT_NODE+384+o;          stride=512; break;
            case 4: v1=a.amul_v;  g1=a.amul_g;  dst=ws+OFF_WT_AMUL+o;              stride=128; break;
            case 5: v1=a.neigh_v; g1=a.neigh_g; dst=ws+OFF_WT_FINAL+o;             stride=128; break;
            case 6: v1=a.neigh2_v;g1=a.neigh2_g;dst=ws+OFF_WT_FINAL+128*128+o;     stride=128; break;
            case 7: v1=a.self_v;  g1=a.self_g;  dst=ws+OFF_WT_FINAL+256*128+o;     stride=128; break;
            case 8: v1=a.mlp_v;        g1=a.mlp_g;     dst=ws+OFF_WT_MLP+o;        stride=128; break;
            case 9: v1=a.mlp_v+16384;  g1=a.mlp_g+128; dst=ws+OFF_WT_MLP+16384+o;  stride=128; break;
        }
        float x1 = v1[o*128 + i];
        float n1 = sqrtf(block_sum128(x1*x1, sbuf));
        float w = g1[o] * x1 / n1;
        if (v2) {
            float x2 = v2[o*128 + i];
            float n2 = sqrtf(block_sum128(x2*x2, sbuf));
            w += sgn2 * g2[o] * x2 / n2;
        }
        dst[i * stride] = w;
    } else {
        float v = a.aout_v[i];
        float n = sqrtf(block_sum128(v*v, sbuf));
        ws[OFF_WAOUT + i] = a.aout_g[0] * v / n;
        ws[OFF_BE + i]    = a.asrc_b[i] + a.adst_b[i] + a.asub_b[i] + a.amul_b[i];
        ws[OFF_BFIN + i]  = a.self_b[i] + a.neigh_b[i] + a.neigh2_b[i];
        if (i == 0) ws[OFF_BAOUT] = a.aout_b[0];
    }
}

// ---------------- bf16 conversions ----------------
__global__ __launch_bounds__(256) void convert_feat_kernel(const float* __restrict__ feat,
                                                           unsigned short* __restrict__ featbf) {
    int i = (blockIdx.x * 256 + threadIdx.x) * 8;
    float4 v0 = ((const float4*)feat)[i >> 2];
    float4 v1 = ((const float4*)feat)[(i >> 2) + 1];
    uint4 p;
    p.x = (unsigned)f2bf(v0.x) | ((unsigned)f2bf(v0.y) << 16);
    p.y = (unsigned)f2bf(v0.z) | ((unsigned)f2bf(v0.w) << 16);
    p.z = (unsigned)f2bf(v1.x) | ((unsigned)f2bf(v1.y) << 16);
    p.w = (unsigned)f2bf(v1.z) | ((unsigned)f2bf(v1.w) << 16);
    *(uint4*)&featbf[i] = p;
}

// amul weights: ws [k][o] f32 -> wtbf [o][k] bf16
__global__ __launch_bounds__(256) void convert_wt_kernel(const float* __restrict__ ws,
                                                         unsigned short* __restrict__ wtbf) {
    int idx = blockIdx.x * 256 + threadIdx.x;
    int o = idx >> 7, k = idx & 127;
    wtbf[o * 128 + k] = f2bf(ws[OFF_WT_AMUL + k * 128 + o]);
}

// ---------------- CSR-by-dst construction ----------------
__global__ __launch_bounds__(256) void hist_zero_kernel(float* __restrict__ ws) {
    int i = blockIdx.x * 256 + threadIdx.x;
    if (i < NN) ((int*)(ws + OFF_HIST))[i] = 0;
}

__global__ __launch_bounds__(256) void hist_kernel(const int* __restrict__ dst, float* __restrict__ ws) {
    int e = blockIdx.x * 256 + threadIdx.x;
    if (e < EE) atomicAdd(&((int*)(ws + OFF_HIST))[dst[e]], 1);
}

__global__ __launch_bounds__(1024) void scan_kernel(float* __restrict__ ws) {
    __shared__ int sp[1024];
    const int* hist = (const int*)(ws + OFF_HIST);
    int* starts = (int*)(ws + OFF_STARTS);
    int* cursor = (int*)(ws + OFF_CURSOR);
    int t = threadIdx.x;
    const int C = 49;  // 1024*49 >= 50000
    int base = t * C;
    int local = 0;
    for (int j = 0; j < C; ++j) { int idx = base + j; if (idx < NN) local += hist[idx]; }
    sp[t] = local;
    __syncthreads();
    for (int o = 1; o < 1024; o <<= 1) {
        int v = (t >= o) ? sp[t - o] : 0;
        __syncthreads();
        sp[t] += v;
        __syncthreads();
    }
    int run = sp[t] - local;  // exclusive prefix
    for (int j = 0; j < C; ++j) {
        int idx = base + j;
        if (idx < NN) { starts[idx] = run; cursor[idx] = run; run += hist[idx]; }
    }
    if (t == 0) starts[NN] = EE;
}

__global__ __launch_bounds__(256) void scatteridx_kernel(const int* __restrict__ src,
                                                         const int* __restrict__ dst,
                                                         float* __restrict__ ws) {
    int e = blockIdx.x * 256 + threadIdx.x;
    if (e >= EE) return;
    int d = dst[e];
    int pos = atomicAdd(&((int*)(ws + OFF_CURSOR))[d], 1);
    ((int*)(ws + OFF_SSRC))[pos] = src[e];
    ws[OFF_SEV + pos] = ws[OFF_E + e];
}

// ---------------- segmented reduction: one wave per dst node ----------------
__global__ __launch_bounds__(256) void segreduce_kernel(float* __restrict__ ws) {
    int n = blockIdx.x * 4 + (threadIdx.x >> 6);
    int lane = threadIdx.x & 63;
    const int* starts = (const int*)(ws + OFF_STARTS);
    const int* ssrc = (const int*)(ws + OFF_SSRC);
    const float* sev = ws + OFF_SEV;
    const float* Cn = ws + OFF_CNODE;
    int s0 = starts[n], s1 = starts[n + 1];
    float2 mx = make_float2(-INFINITY, -INFINITY);
    float2 sm = make_float2(0.f, 0.f);
    for (int i = s0; i < s1; ++i) {
        int s = ssrc[i];
        float ev = sev[i];
        float2 h  = *(const float2*)&Cn[s * 512 + 256 + lane * 2];
        float2 h2 = *(const float2*)&Cn[s * 512 + 384 + lane * 2];
        mx.x = fmaxf(mx.x, ev * h.x);  mx.y = fmaxf(mx.y, ev * h.y);
        sm.x += ev * h2.x;             sm.y += ev * h2.y;
    }
    int cnt = s1 - s0;
    if (cnt == 0) { mx.x = 0.f; mx.y = 0.f; }
    float ic = 1.0f / (float)max(cnt, 1);
    *(float2*)&ws[OFF_NEIGH  + n * 128 + lane * 2] = mx;
    *(float2*)&ws[OFF_NEIGH2 + n * 128 + lane * 2] = make_float2(sm.x * ic, sm.y * ic);
}

// ---------------- node GEMM: fp32 tile, gy 0/1 -> bf16 S table, gy 2/3 -> f32 h/h2 ----------------
__global__ __launch_bounds__(256) void gemm_node(const float* __restrict__ feat,
                                                 const float* __restrict__ pool_b,
                                                 const float* __restrict__ pool2_b,
                                                 unsigned short* __restrict__ sbf,
                                                 float* __restrict__ ws) {
    __shared__ float As[64 * 36];
    __shared__ float Bs[32 * 132];
    const float* WT = ws + OFF_WT_NODE;
    float* C = ws + OFF_CNODE;
    int tid = threadIdx.x, tx = tid & 15, ty = tid >> 4;
    int row0 = blockIdx.x * 64;
    int gy = blockIdx.y, n0 = gy * 128;
    float acc[4][8] = {};
    for (int k0 = 0; k0 < 128; k0 += 32) {
        #pragma unroll
        for (int it = 0; it < 2; ++it) {
            int idx = tid + it * 256;
            int r = idx >> 3, kq = idx & 7;
            int rr = min(row0 + r, NN - 1);
            float4 v = ((const float4*)feat)[rr * 32 + (k0 >> 2) + kq];
            ((float4*)As)[r * 9 + kq] = v;
        }
        #pragma unroll
        for (int it = 0; it < 4; ++it) {
            int idx = tid + it * 256;
            int kk = idx >> 5, cq = idx & 31;
            float4 v = ((const float4*)WT)[(k0 + kk) * 128 + (n0 >> 2) + cq];
            ((float4*)Bs)[kk * 33 + cq] = v;
        }
        __syncthreads();
        #pragma unroll 4
        for (int kk = 0; kk < 32; ++kk) {
            float4 b0 = ((const float4*)Bs)[kk * 33 + tx];
            float4 b1 = ((const float4*)Bs)[kk * 33 + 16 + tx];
            #pragma unroll
            for (int j = 0; j < 4; ++j) {
                float av = As[(ty * 4 + j) * 36 + kk];
                acc[j][0] += av * b0.x; acc[j][1] += av * b0.y;
                acc[j][2] += av * b0.z; acc[j][3] += av * b0.w;
                acc[j][4] += av * b1.x; acc[j][5] += av * b1.y;
                acc[j][6] += av * b1.z; acc[j][7] += av * b1.w;
            }
        }
        __syncthreads();
    }
    #pragma unroll
    for (int j = 0; j < 4; ++j) {
        int row = row0 + ty * 4 + j;
        if (row >= NN) continue;
        #pragma unroll
        for (int g = 0; g < 2; ++g) {
            int c = g * 64 + tx * 4;
            float4 v = make_float4(acc[j][g*4+0], acc[j][g*4+1], acc[j][g*4+2], acc[j][g*4+3]);
            if (gy == 0) {
                ushort4 u = make_ushort4(f2bf(v.x), f2bf(v.y), f2bf(v.z), f2bf(v.w));
                *(ushort4*)&sbf[row * 256 + c] = u;
            } else if (gy == 1) {
                ushort4 u = make_ushort4(f2bf(v.x), f2bf(v.y), f2bf(v.z), f2bf(v.w));
                *(ushort4*)&sbf[row * 256 + 128 + c] = u;
            } else if (gy == 2) {
                v.x = gelu_f(v.x + pool_b[c+0]); v.y = gelu_f(v.y + pool_b[c+1]);
                v.z = gelu_f(v.z + pool_b[c+2]); v.w = gelu_f(v.w + pool_b[c+3]);
                ((float4*)C)[(row * 512 + 256 + c) >> 2] = v;
            } else {
                v.x = gelu_f(v.x + pool2_b[c+0]); v.y = gelu_f(v.y + pool2_b[c+1]);
                v.z = gelu_f(v.z + pool2_b[c+2]); v.w = gelu_f(v.w + pool2_b[c+3]);
                ((float4*)C)[(row * 512 + 384 + c) >> 2] = v;
            }
        }
    }
}

// ---------------- edge GEMM (bf16 MFMA) + fused attention epilogue -> e[E] ----------------
// Tile: 64 edges x 128 outs, K=128. 4 waves; wave w owns edges [w*16, w*16+16).
// A (product) staged in LDS bf16, MFMA A-frag layout, row pad +8 bf16.
// B = wtbf [o][k] bf16, fragment-gathered directly from global (L2-resident 32 KB).
__global__ __launch_bounds__(256) void gemm_edge(const int* __restrict__ src,
                                                 const int* __restrict__ dst,
                                                 const unsigned short* __restrict__ featbf,
                                                 const unsigned short* __restrict__ wtbf,
                                                 const unsigned short* __restrict__ sbf,
                                                 float* __restrict__ ws) {
    __shared__ unsigned short As[64 * 136];
    __shared__ int sI[64], dI[64];
    __shared__ float waout_s[128], be_s[128];
    int tid = threadIdx.x;
    int e0 = blockIdx.x * 64;
    if (tid < 64) { sI[tid] = src[e0 + tid]; dI[tid] = dst[e0 + tid]; }
    else if (tid < 192) { int i = tid - 64; waout_s[i] = ws[OFF_WAOUT + i]; be_s[i] = ws[OFF_BE + i]; }
    float b_aout = ws[OFF_BAOUT];
    float* e_out = ws + OFF_E;

    // stage A = bf16(fs*fd): 64 rows x 16 units of 8 bf16
    #pragma unroll
    for (int it = 0; it < 4; ++it) {
        int idx = tid + it * 256;
        int r = idx >> 4, u = idx & 15;
        int s = src[e0 + r], d = dst[e0 + r];
        uint4 av = *(const uint4*)&featbf[s * 128 + u * 8];
        uint4 bv = *(const uint4*)&featbf[d * 128 + u * 8];
        uint4 m;
        m.x = mulpack(av.x, bv.x); m.y = mulpack(av.y, bv.y);
        m.z = mulpack(av.z, bv.z); m.w = mulpack(av.w, bv.w);
        *(uint4*)&As[r * 136 + u * 8] = m;
    }
    __syncthreads();

    int lane = tid & 63, w = tid >> 6;
    int quad = lane >> 4, l15 = lane & 15;
    f32x4 acc[8] = {};
    #pragma unroll 1
    for (int ks = 0; ks < 4; ++ks) {
        bf16x8 a = *(const bf16x8*)&As[(w * 16 + l15) * 136 + ks * 32 + quad * 8];
        #pragma unroll
        for (int t = 0; t < 8; ++t) {
            bf16x8 b = *(const bf16x8*)&wtbf[(t * 16 + l15) * 128 + ks * 32 + quad * 8];
            acc[t] = __builtin_amdgcn_mfma_f32_16x16x32_bf16(a, b, acc[t], 0, 0, 0);
        }
    }

    // epilogue: pre[row][col] = acc + S_src[s][col] + S_dst[d][col] + be; gelu; dot waout; reduce 16 lanes
    #pragma unroll
    for (int reg = 0; reg < 4; ++reg) {
        int r = w * 16 + quad * 4 + reg;
        int s = sI[r], d = dI[r];
        float partial = 0.0f;
        #pragma unroll
        for (int t = 0; t < 8; ++t) {
            int col = t * 16 + l15;
            float v = acc[t][reg]
                    + bf2f(sbf[s * 256 + col])
                    + bf2f(sbf[d * 256 + 128 + col])
                    + be_s[col];
            partial += gelu_f(v) * waout_s[col];
        }
        partial += __shfl_xor(partial, 1, 16);
        partial += __shfl_xor(partial, 2, 16);
        partial += __shfl_xor(partial, 4, 16);
        partial += __shfl_xor(partial, 8, 16);
        if (l15 == 0) e_out[e0 + r] = leaky_f(partial + b_aout);
    }
}

// ---------------- final GEMM: rst[N][128] = [neigh, neigh2, feat] @ WT_final + b_final ----------------
__global__ __launch_bounds__(256) void gemm_final(const float* __restrict__ feat,
                                                  float* __restrict__ out,
                                                  float* __restrict__ ws) {
    __shared__ float As[64 * 36];
    __shared__ float Bs[32 * 132];
    int tid = threadIdx.x, tx = tid & 15, ty = tid >> 4;
    int row0 = blockIdx.x * 64;
    const float* WT = ws + OFF_WT_FINAL;
    const float* neigh  = ws + OFF_NEIGH;
    const float* neigh2 = ws + OFF_NEIGH2;
    const float* bfin   = ws + OFF_BFIN;
    float acc[4][8] = {};
    for (int k0 = 0; k0 < 384; k0 += 32) {
        #pragma unroll
        for (int it = 0; it < 2; ++it) {
            int idx = tid + it * 256;
            int r = idx >> 3, kq = idx & 7;
            int rr = min(row0 + r, NN - 1);
            int kg = k0 + kq * 4;
            float4 v;
            if (k0 < 128) {
                v = ((const float4*)neigh)[rr * 32 + (kg >> 2)];
            } else if (k0 < 256) {
                v = ((const float4*)neigh2)[rr * 32 + ((kg - 128) >> 2)];
            } else {
                v = ((const float4*)feat)[rr * 32 + ((kg - 256) >> 2)];
            }
            ((float4*)As)[r * 9 + kq] = v;
        }
        #pragma unroll
        for (int it = 0; it < 4; ++it) {
            int idx = tid + it * 256;
            int kk = idx >> 5, cq = idx & 31;
            float4 v = ((const float4*)WT)[(k0 + kk) * 32 + cq];
            ((float4*)Bs)[kk * 33 + cq] = v;
        }
        __syncthreads();
        #pragma unroll 4
        for (int kk = 0; kk < 32; ++kk) {
            float4 b0 = ((const float4*)Bs)[kk * 33 + tx];
            float4 b1 = ((const float4*)Bs)[kk * 33 + 16 + tx];
            #pragma unroll
            for (int j = 0; j < 4; ++j) {
                float av = As[(ty * 4 + j) * 36 + kk];
                acc[j][0] += av * b0.x; acc[j][1] += av * b0.y;
                acc[j][2] += av * b0.z; acc[j][3] += av * b0.w;
                acc[j][4] += av * b1.x; acc[j][5] += av * b1.y;
                acc[j][6] += av * b1.z; acc[j][7] += av * b1.w;
            }
        }
        __syncthreads();
    }
    #pragma unroll
    for (int j = 0; j < 4; ++j) {
        int row = row0 + ty * 4 + j;
        if (row >= NN) continue;
        #pragma unroll
        for (int g = 0; g < 2; ++g) {
            int c = g * 64 + tx * 4;
            float4 v = make_float4(acc[j][g*4+0] + bfin[c+0], acc[j][g*4+1] + bfin[c+1],
                                   acc[j][g*4+2] + bfin[c+2], acc[j][g*4+3] + bfin[c+3]);
            ((float4*)out)[(row * 128 + c) >> 2] = v;
        }
    }
}

// ---------------- MLP layer ----------------
__global__ __launch_bounds__(256) void gemm_mlp(const float* __restrict__ rst_in,
                                                float* __restrict__ out,
                                                const float* __restrict__ mlp_b,
                                                int layer,
                                                float* __restrict__ ws) {
    __shared__ float As[64 * 36];
    __shared__ float Bs[32 * 132];
    int tid = threadIdx.x, tx = tid & 15, ty = tid >> 4;
    int row0 = blockIdx.x * 64;
    const float* WT = ws + OFF_WT_MLP + layer * 16384;
    const float* bias = mlp_b + layer * 128;
    float acc[4][8] = {};
    for (int k0 = 0; k0 < 128; k0 += 32) {
        #pragma unroll
        for (int it = 0; it < 2; ++it) {
            int idx = tid + it * 256;
            int r = idx >> 3, kq = idx & 7;
            int rr = min(row0 + r, NN - 1);
            float4 v = ((const float4*)rst_in)[rr * 32 + (k0 >> 2) + kq];
            v.x = gelu_f(v.x); v.y = gelu_f(v.y); v.z = gelu_f(v.z); v.w = gelu_f(v.w);
            ((float4*)As)[r * 9 + kq] = v;
        }
        #pragma unroll
        for (int it = 0; it < 4; ++it) {
            int idx = tid + it * 256;
            int kk = idx >> 5, cq = idx & 31;
            float4 v = ((const float4*)WT)[(k0 + kk) * 32 + cq];
            ((float4*)Bs)[kk * 33 + cq] = v;
        }
        __syncthreads();
        #pragma unroll 4
        for (int kk = 0; kk < 32; ++kk) {
            float4 b0 = ((const float4*)Bs)[kk * 33 + tx];
            float4 b1 = ((const float4*)Bs)[kk * 33 + 16 + tx];
            #pragma unroll
            for (int j = 0; j < 4; ++j) {
                float av = As[(ty * 4 + j) * 36 + kk];
                acc[j][0] += av * b0.x; acc[j][1] += av * b0.y;
                acc[j][2] += av * b0.z; acc[j][3] += av * b0.w;
                acc[j][4] += av * b1.x; acc[j][5] += av * b1.y;
                acc[j][6] += av * b1.z; acc[j][7] += av * b1.w;
            }
        }
        __syncthreads();
    }
    #pragma unroll
    for (int j = 0; j < 4; ++j) {
        int row = row0 + ty * 4 + j;
        if (row >= NN) continue;
        #pragma unroll
        for (int g = 0; g < 2; ++g) {
            int c = g * 64 + tx * 4;
            float4 old = ((const float4*)rst_in)[(row * 128 + c) >> 2];
            float4 v = make_float4(old.x + acc[j][g*4+0] + bias[c+0],
                                   old.y + acc[j][g*4+1] + bias[c+1],
                                   old.z + acc[j][g*4+2] + bias[c+2],
                                   old.w + acc[j][g*4+3] + bias[c+3]);
            ((float4*)out)[(row * 128 + c) >> 2] = v;
        }
    }
}

// ---------------- host launch ----------------
extern "C" void kernel_launch(void* const* d_in, const int* in_sizes, int n_in,
                              void* d_out, int out_size, void* d_ws, size_t ws_size,
                              hipStream_t stream) {
    const float* feat = (const float*)d_in[0];
    WnormArgs wa;
    wa.asrc_v = (const float*)d_in[1];  wa.asrc_g = (const float*)d_in[2];  wa.asrc_b = (const float*)d_in[3];
    wa.adst_v = (const float*)d_in[4];  wa.adst_g = (const float*)d_in[5];  wa.adst_b = (const float*)d_in[6];
    wa.asub_v = (const float*)d_in[7];  wa.asub_g = (const float*)d_in[8];  wa.asub_b = (const float*)d_in[9];
    wa.amul_v = (const float*)d_in[10]; wa.amul_g = (const float*)d_in[11]; wa.amul_b = (const float*)d_in[12];
    wa.aout_v = (const float*)d_in[13]; wa.aout_g = (const float*)d_in[14]; wa.aout_b = (const float*)d_in[15];
    wa.pool_v = (const float*)d_in[16]; wa.pool_g = (const float*)d_in[17]; wa.pool_b = (const float*)d_in[18];
    wa.pool2_v= (const float*)d_in[19]; wa.pool2_g= (const float*)d_in[20]; wa.pool2_b= (const float*)d_in[21];
    wa.self_v = (const float*)d_in[22]; wa.self_g = (const float*)d_in[23]; wa.self_b = (const float*)d_in[24];
    wa.neigh_v= (const float*)d_in[25]; wa.neigh_g= (const float*)d_in[26]; wa.neigh_b= (const float*)d_in[27];
    wa.neigh2_v=(const float*)d_in[28]; wa.neigh2_g=(const float*)d_in[29]; wa.neigh2_b=(const float*)d_in[30];
    wa.mlp_v  = (const float*)d_in[31]; wa.mlp_g  = (const float*)d_in[32]; wa.mlp_b  = (const float*)d_in[33];
    const int* src = (const int*)d_in[34];
    const int* dst = (const int*)d_in[35];
    float* out = (float*)d_out;
    float* ws = (float*)d_ws;
    wa.ws = ws;
    unsigned short* featbf = (unsigned short*)(ws + OFF_NEIGH);
    unsigned short* wtbf   = (unsigned short*)(ws + OFF_NEIGH + 3300000);
    unsigned short* sbf    = (unsigned short*)(ws + OFF_NEIGH2);

    // 1) normalized weights + fused bias vectors
    wnorm_kernel<<<dim3(1281), dim3(128), 0, stream>>>(wa);
    // 2) bf16 conversions (feat anytime; wt after wnorm)
    convert_feat_kernel<<<dim3(NN * 128 / (256 * 8)), dim3(256), 0, stream>>>(feat, featbf);
    convert_wt_kernel<<<dim3(64), dim3(256), 0, stream>>>(ws, wtbf);
    // 3) CSR-by-dst: histogram + scan
    hist_zero_kernel<<<dim3((NN + 255) / 256), dim3(256), 0, stream>>>(ws);
    hist_kernel<<<dim3((EE + 255) / 256), dim3(256), 0, stream>>>(dst, ws);
    scan_kernel<<<dim3(1), dim3(1024), 0, stream>>>(ws);
    // 4) node-level GEMM: S table (bf16) + h/h2 (f32)
    gemm_node<<<dim3(782, 4), dim3(256), 0, stream>>>(feat, wa.pool_b, wa.pool2_b, sbf, ws);
    // 5) edge GEMM (MFMA bf16) + fused attention epilogue -> e[E]
    gemm_edge<<<dim3(EE / 64), dim3(256), 0, stream>>>(src, dst, featbf, wtbf, sbf, ws);
    // 6) sort edges by dst (src + e payloads)
    scatteridx_kernel<<<dim3((EE + 255) / 256), dim3(256), 0, stream>>>(src, dst, ws);
    // 7) segmented reduce: one wave per dst node -> neigh (max, zeroed), neigh2 (mean)
    //    (overwrites the featbf/wtbf/sbf alias regions — safe, gemm_edge is done)
    segreduce_kernel<<<dim3(NN / 4), dim3(256), 0, stream>>>(ws);
    // 8) final fused GEMM -> rst (d_out)
    gemm_final<<<dim3(782), dim3(256), 0, stream>>>(feat, out, ws);
    // 9) two residual MLP layers (in-place, row-wise safe)
    gemm_mlp<<<dim3(782), dim3(256), 0, stream>>>(out, out, wa.mlp_b, 0, ws);
    gemm_mlp<<<dim3(782), dim3(256), 0, stream>>>(out, out, wa.mlp_b, 1, ws);
}

// Round 4
// 942.966 us; speedup vs baseline: 2.7303x; 1.1414x over previous
//
#include <hip/hip_runtime.h>
#include <math.h>

// ---------------- problem constants ----------------
constexpr int NN = 50000;   // nodes
constexpr int EE = 800000;  // edges

// ---------------- workspace layout (float offsets) ----------------
constexpr int OFF_WT_NODE  = 0;                    // [128][512] k-major: cols 0:asrc+asub 1:adst-asub 2:pool 3:pool2
constexpr int OFF_WT_AMUL  = 65536;                // [128][128] k-major f32
constexpr int OFF_WT_FINAL = 81920;                // [384][128] rows: 0-127 neigh, 128-255 neigh2, 256-383 self
constexpr int OFF_WT_MLP   = 131072;               // 2 x [128][128]
constexpr int OFF_WAOUT    = 163840;               // [128]
constexpr int OFF_BE       = 163968;               // [128] b_asrc+b_adst+b_asub+b_amul
constexpr int OFF_BFIN     = 164096;               // [128] b_self+b_neigh+b_neigh2
constexpr int OFF_BAOUT    = 164224;               // [1] (padded to 16)
// big arrays
constexpr int OFF_HBF      = 164240;               // [N][256] bf16 (h | h2) = N*128 float slots
constexpr int OFF_SEV      = OFF_HBF + NN*128;     // [E] f32: e in dst-sorted order (written by gemm_edge)
constexpr int OFF_NEIGH    = OFF_SEV + EE;         // [N][128] f32 segreduce out
constexpr int OFF_NEIGH2   = OFF_NEIGH + NN*128;   // [N][128] f32 segreduce out
constexpr int OFF_HIST     = OFF_NEIGH2 + NN*128;  // [N] int
constexpr int OFF_STARTS   = OFF_HIST + NN;        // [N+1] int (+pad)
constexpr int OFF_CURSOR   = OFF_STARTS + NN + 8;  // [N] int
constexpr int OFF_SSRC     = OFF_CURSOR + NN;      // [E] int (src sorted by dst)
constexpr int OFF_SDST     = OFF_SSRC + EE;        // [E] int (dst sorted by dst)
// bf16 aliases (regions only written AFTER gemm_edge completes):
//   featbf : N*128 bf16 (3.2M float slots)  -> aliases OFF_NEIGH
//   wtbf   : 128*128 bf16 (amul^T [o][k])   -> aliases OFF_NEIGH + 3300000
//   sbf    : N*256 bf16 (S_src|S_dst)       -> aliases OFF_NEIGH2 (exactly fills it)

typedef __attribute__((ext_vector_type(8))) short bf16x8;
typedef __attribute__((ext_vector_type(4))) float f32x4;

// ---------------- device helpers ----------------
__device__ __forceinline__ float gelu_f(float x) {
    return 0.5f * x * (1.0f + erff(x * 0.70710678118654752440f));
}
__device__ __forceinline__ float leaky_f(float x) {
    return x > 0.0f ? x : 0.2f * x;
}
__device__ __forceinline__ unsigned short f2bf(float x) {
    unsigned u = __float_as_uint(x);
    return (unsigned short)((u + 0x7fffu + ((u >> 16) & 1u)) >> 16);
}
__device__ __forceinline__ float bf2f(unsigned short b) {
    return __uint_as_float(((unsigned)b) << 16);
}
__device__ __forceinline__ unsigned mulpack(unsigned a, unsigned b) {
    float a0 = __uint_as_float(a << 16), a1 = __uint_as_float(a & 0xffff0000u);
    float b0 = __uint_as_float(b << 16), b1 = __uint_as_float(b & 0xffff0000u);
    return (unsigned)f2bf(a0 * b0) | ((unsigned)f2bf(a1 * b1) << 16);
}
__device__ __forceinline__ float block_sum128(float v, float* sbuf) {
    #pragma unroll
    for (int o = 32; o > 0; o >>= 1) v += __shfl_down(v, o, 64);
    int lane = threadIdx.x & 63, w = threadIdx.x >> 6;
    if (lane == 0) sbuf[w] = v;
    __syncthreads();
    float r = sbuf[0] + sbuf[1];
    __syncthreads();
    return r;
}

// ---------------- weight normalization ----------------
struct WnormArgs {
    const float *asrc_v, *asrc_g, *asrc_b;
    const float *adst_v, *adst_g, *adst_b;
    const float *asub_v, *asub_g, *asub_b;
    const float *amul_v, *amul_g, *amul_b;
    const float *aout_v, *aout_g, *aout_b;
    const float *pool_v, *pool_g, *pool_b;
    const float *pool2_v, *pool2_g, *pool2_b;
    const float *self_v, *self_g, *self_b;
    const float *neigh_v, *neigh_g, *neigh_b;
    const float *neigh2_v, *neigh2_g, *neigh2_b;
    const float *mlp_v, *mlp_g, *mlp_b;
    float* ws;
};

__global__ __launch_bounds__(128) void wnorm_kernel(WnormArgs a) {
    __shared__ float sbuf[2];
    int bid = blockIdx.x, i = threadIdx.x;
    float* ws = a.ws;
    if (bid < 1280) {
        int o = bid & 127, grp = bid >> 7;
        const float *v1 = nullptr, *g1 = nullptr, *v2 = nullptr, *g2 = nullptr;
        float sgn2 = 1.0f; float* dst = nullptr; int stride = 0;
        switch (grp) {
            case 0: v1=a.asrc_v; g1=a.asrc_g; v2=a.asub_v; g2=a.asub_g; sgn2= 1.f; dst=ws+OFF_WT_NODE+o;        stride=512; break;
            case 1: v1=a.adst_v; g1=a.adst_g; v2=a.asub_v; g2=a.asub_g; sgn2=-1.f; dst=ws+OFF_WT_NODE+128+o;    stride=512; break;
            case 2: v1=a.pool_v;  g1=a.pool_g;  dst=ws+OFF_WT_NODE+256+o;          stride=512; break;
            case 3: v1=a.pool2_v; g1=a.pool2_g; dst=ws+OFF_WT_NODE+384+o;          stride=512; break;
            case 4: v1=a.amul_v;  g1=a.amul_g;  dst=ws+OFF_WT_AMUL+o;              stride=128; break;
            case 5: v1=a.neigh_v; g1=a.neigh_g; dst=ws+OFF_WT_FINAL+o;             stride=128; break;
            case 6: v1=a.neigh2_v;g1=a.neigh2_g;dst=ws+OFF_WT_FINAL+128*128+o;     stride=128; break;
            case 7: v1=a.self_v;  g1=a.self_g;  dst=ws+OFF_WT_FINAL+256*128+o;     stride=128; break;
            case 8: v1=a.mlp_v;        g1=a.mlp_g;     dst=ws+OFF_WT_MLP+o;        stride=128; break;
            case 9: v1=a.mlp_v+16384;  g1=a.mlp_g+128; dst=ws+OFF_WT_MLP+16384+o;  stride=128; break;
        }
        float x1 = v1[o*128 + i];
        float n1 = sqrtf(block_sum128(x1*x1, sbuf));
        float w = g1[o] * x1 / n1;
        if (v2) {
            float x2 = v2[o*128 + i];
            float n2 = sqrtf(block_sum128(x2*x2, sbuf));
            w += sgn2 * g2[o] * x2 / n2;
        }
        dst[i * stride] = w;
    } else {
        float v = a.aout_v[i];
        float n = sqrtf(block_sum128(v*v, sbuf));
        ws[OFF_WAOUT + i] = a.aout_g[0] * v / n;
        ws[OFF_BE + i]    = a.asrc_b[i] + a.adst_b[i] + a.asub_b[i] + a.amul_b[i];
        ws[OFF_BFIN + i]  = a.self_b[i] + a.neigh_b[i] + a.neigh2_b[i];
        if (i == 0) ws[OFF_BAOUT] = a.aout_b[0];
    }
}

// ---------------- bf16 conversions ----------------
__global__ __launch_bounds__(256) void convert_feat_kernel(const float* __restrict__ feat,
                                                           unsigned short* __restrict__ featbf) {
    int i = (blockIdx.x * 256 + threadIdx.x) * 8;
    float4 v0 = ((const float4*)feat)[i >> 2];
    float4 v1 = ((const float4*)feat)[(i >> 2) + 1];
    uint4 p;
    p.x = (unsigned)f2bf(v0.x) | ((unsigned)f2bf(v0.y) << 16);
    p.y = (unsigned)f2bf(v0.z) | ((unsigned)f2bf(v0.w) << 16);
    p.z = (unsigned)f2bf(v1.x) | ((unsigned)f2bf(v1.y) << 16);
    p.w = (unsigned)f2bf(v1.z) | ((unsigned)f2bf(v1.w) << 16);
    *(uint4*)&featbf[i] = p;
}

// amul weights: ws [k][o] f32 -> wtbf [o][k] bf16
__global__ __launch_bounds__(256) void convert_wt_kernel(const float* __restrict__ ws,
                                                         unsigned short* __restrict__ wtbf) {
    int idx = blockIdx.x * 256 + threadIdx.x;
    int o = idx >> 7, k = idx & 127;
    wtbf[o * 128 + k] = f2bf(ws[OFF_WT_AMUL + k * 128 + o]);
}

// ---------------- CSR-by-dst construction (runs BEFORE gemm_edge) ----------------
__global__ __launch_bounds__(256) void hist_zero_kernel(float* __restrict__ ws) {
    int i = blockIdx.x * 256 + threadIdx.x;
    if (i < NN) ((int*)(ws + OFF_HIST))[i] = 0;
}

__global__ __launch_bounds__(256) void hist_kernel(const int* __restrict__ dst, float* __restrict__ ws) {
    int e = blockIdx.x * 256 + threadIdx.x;
    if (e < EE) atomicAdd(&((int*)(ws + OFF_HIST))[dst[e]], 1);
}

__global__ __launch_bounds__(1024) void scan_kernel(float* __restrict__ ws) {
    __shared__ int sp[1024];
    const int* hist = (const int*)(ws + OFF_HIST);
    int* starts = (int*)(ws + OFF_STARTS);
    int* cursor = (int*)(ws + OFF_CURSOR);
    int t = threadIdx.x;
    const int C = 49;  // 1024*49 >= 50000
    int base = t * C;
    int local = 0;
    for (int j = 0; j < C; ++j) { int idx = base + j; if (idx < NN) local += hist[idx]; }
    sp[t] = local;
    __syncthreads();
    for (int o = 1; o < 1024; o <<= 1) {
        int v = (t >= o) ? sp[t - o] : 0;
        __syncthreads();
        sp[t] += v;
        __syncthreads();
    }
    int run = sp[t] - local;  // exclusive prefix
    for (int j = 0; j < C; ++j) {
        int idx = base + j;
        if (idx < NN) { starts[idx] = run; cursor[idx] = run; run += hist[idx]; }
    }
    if (t == 0) starts[NN] = EE;
}

__global__ __launch_bounds__(256) void scatteridx_kernel(const int* __restrict__ src,
                                                         const int* __restrict__ dst,
                                                         float* __restrict__ ws) {
    int e = blockIdx.x * 256 + threadIdx.x;
    if (e >= EE) return;
    int d = dst[e];
    int pos = atomicAdd(&((int*)(ws + OFF_CURSOR))[d], 1);
    ((int*)(ws + OFF_SSRC))[pos] = src[e];
    ((int*)(ws + OFF_SDST))[pos] = d;
}

// ---------------- segmented reduction: one wave per dst node, bf16 h/h2 gathers ----------------
__global__ __launch_bounds__(256) void segreduce_kernel(float* __restrict__ ws) {
    int n = blockIdx.x * 4 + (threadIdx.x >> 6);
    int lane = threadIdx.x & 63;
    const int* starts = (const int*)(ws + OFF_STARTS);
    const int* ssrc = (const int*)(ws + OFF_SSRC);
    const float* sev = ws + OFF_SEV;
    const unsigned short* hbf = (const unsigned short*)(ws + OFF_HBF);
    int s0 = starts[n], s1 = starts[n + 1];
    float2 mx = make_float2(-INFINITY, -INFINITY);
    float2 sm = make_float2(0.f, 0.f);
    for (int i = s0; i < s1; ++i) {
        int s = ssrc[i];
        float ev = sev[i];
        unsigned hv  = *(const unsigned*)&hbf[s * 256 + lane * 2];
        unsigned h2v = *(const unsigned*)&hbf[s * 256 + 128 + lane * 2];
        float hx = bf2f((unsigned short)(hv & 0xffffu)),  hy = bf2f((unsigned short)(hv >> 16));
        float gx = bf2f((unsigned short)(h2v & 0xffffu)), gy = bf2f((unsigned short)(h2v >> 16));
        mx.x = fmaxf(mx.x, ev * hx); mx.y = fmaxf(mx.y, ev * hy);
        sm.x += ev * gx;             sm.y += ev * gy;
    }
    int cnt = s1 - s0;
    if (cnt == 0) { mx.x = 0.f; mx.y = 0.f; }
    float ic = 1.0f / (float)max(cnt, 1);
    *(float2*)&ws[OFF_NEIGH  + n * 128 + lane * 2] = mx;
    *(float2*)&ws[OFF_NEIGH2 + n * 128 + lane * 2] = make_float2(sm.x * ic, sm.y * ic);
}

// ---------------- node GEMM: fp32 tile; gy 0/1 -> bf16 S table; gy 2/3 -> bf16 h/h2 ----------------
__global__ __launch_bounds__(256) void gemm_node(const float* __restrict__ feat,
                                                 const float* __restrict__ pool_b,
                                                 const float* __restrict__ pool2_b,
                                                 unsigned short* __restrict__ sbf,
                                                 unsigned short* __restrict__ hbf,
                                                 float* __restrict__ ws) {
    __shared__ float As[64 * 36];
    __shared__ float Bs[32 * 132];
    const float* WT = ws + OFF_WT_NODE;
    int tid = threadIdx.x, tx = tid & 15, ty = tid >> 4;
    int row0 = blockIdx.x * 64;
    int gy = blockIdx.y, n0 = gy * 128;
    float acc[4][8] = {};
    for (int k0 = 0; k0 < 128; k0 += 32) {
        #pragma unroll
        for (int it = 0; it < 2; ++it) {
            int idx = tid + it * 256;
            int r = idx >> 3, kq = idx & 7;
            int rr = min(row0 + r, NN - 1);
            float4 v = ((const float4*)feat)[rr * 32 + (k0 >> 2) + kq];
            ((float4*)As)[r * 9 + kq] = v;
        }
        #pragma unroll
        for (int it = 0; it < 4; ++it) {
            int idx = tid + it * 256;
            int kk = idx >> 5, cq = idx & 31;
            float4 v = ((const float4*)WT)[(k0 + kk) * 128 + (n0 >> 2) + cq];
            ((float4*)Bs)[kk * 33 + cq] = v;
        }
        __syncthreads();
        #pragma unroll 4
        for (int kk = 0; kk < 32; ++kk) {
            float4 b0 = ((const float4*)Bs)[kk * 33 + tx];
            float4 b1 = ((const float4*)Bs)[kk * 33 + 16 + tx];
            #pragma unroll
            for (int j = 0; j < 4; ++j) {
                float av = As[(ty * 4 + j) * 36 + kk];
                acc[j][0] += av * b0.x; acc[j][1] += av * b0.y;
                acc[j][2] += av * b0.z; acc[j][3] += av * b0.w;
                acc[j][4] += av * b1.x; acc[j][5] += av * b1.y;
                acc[j][6] += av * b1.z; acc[j][7] += av * b1.w;
            }
        }
        __syncthreads();
    }
    #pragma unroll
    for (int j = 0; j < 4; ++j) {
        int row = row0 + ty * 4 + j;
        if (row >= NN) continue;
        #pragma unroll
        for (int g = 0; g < 2; ++g) {
            int c = g * 64 + tx * 4;
            float4 v = make_float4(acc[j][g*4+0], acc[j][g*4+1], acc[j][g*4+2], acc[j][g*4+3]);
            if (gy == 0) {
                *(ushort4*)&sbf[row * 256 + c] = make_ushort4(f2bf(v.x), f2bf(v.y), f2bf(v.z), f2bf(v.w));
            } else if (gy == 1) {
                *(ushort4*)&sbf[row * 256 + 128 + c] = make_ushort4(f2bf(v.x), f2bf(v.y), f2bf(v.z), f2bf(v.w));
            } else if (gy == 2) {
                v.x = gelu_f(v.x + pool_b[c+0]); v.y = gelu_f(v.y + pool_b[c+1]);
                v.z = gelu_f(v.z + pool_b[c+2]); v.w = gelu_f(v.w + pool_b[c+3]);
                *(ushort4*)&hbf[row * 256 + c] = make_ushort4(f2bf(v.x), f2bf(v.y), f2bf(v.z), f2bf(v.w));
            } else {
                v.x = gelu_f(v.x + pool2_b[c+0]); v.y = gelu_f(v.y + pool2_b[c+1]);
                v.z = gelu_f(v.z + pool2_b[c+2]); v.w = gelu_f(v.w + pool2_b[c+3]);
                *(ushort4*)&hbf[row * 256 + 128 + c] = make_ushort4(f2bf(v.x), f2bf(v.y), f2bf(v.z), f2bf(v.w));
            }
        }
    }
}

// ---------------- edge GEMM (bf16 MFMA, dst-sorted order) + fused epilogue -> sev ----------------
// Tile: 64 sorted edges x 128 outs, K=128. Wave w owns edges [w*16, w*16+16).
// A (product) LDS bf16 in MFMA A-frag layout; Ssum (S_src[s]+S_dst[d]) staged f32 in LDS.
// B = wtbf [o][k] bf16 gathered directly from global (L2-resident 32 KB).
__global__ __launch_bounds__(256) void gemm_edge(const unsigned short* __restrict__ featbf,
                                                 const unsigned short* __restrict__ wtbf,
                                                 const unsigned short* __restrict__ sbf,
                                                 float* __restrict__ ws) {
    __shared__ unsigned short As[64 * 136];
    __shared__ float Ssum[64 * 132];
    __shared__ int sI[64], dI[64];
    __shared__ float waout_s[128], be_s[128];
    int tid = threadIdx.x;
    int e0 = blockIdx.x * 64;
    const int* ssrc = (const int*)(ws + OFF_SSRC);
    const int* sdst = (const int*)(ws + OFF_SDST);
    if (tid < 64) { sI[tid] = ssrc[e0 + tid]; dI[tid] = sdst[e0 + tid]; }
    else if (tid < 192) { int i = tid - 64; waout_s[i] = ws[OFF_WAOUT + i]; be_s[i] = ws[OFF_BE + i]; }
    float b_aout = ws[OFF_BAOUT];
    float* e_out = ws + OFF_SEV;
    __syncthreads();

    // stage A = bf16(fs*fd) and Ssum = S_src[s] + S_dst[d] (f32)
    #pragma unroll
    for (int it = 0; it < 4; ++it) {
        int idx = tid + it * 256;
        int r = idx >> 4, u = idx & 15;
        int s = sI[r], d = dI[r];
        uint4 av = *(const uint4*)&featbf[s * 128 + u * 8];
        uint4 bv = *(const uint4*)&featbf[d * 128 + u * 8];
        uint4 m;
        m.x = mulpack(av.x, bv.x); m.y = mulpack(av.y, bv.y);
        m.z = mulpack(av.z, bv.z); m.w = mulpack(av.w, bv.w);
        *(uint4*)&As[r * 136 + u * 8] = m;
        uint4 s1 = *(const uint4*)&sbf[s * 256 + u * 8];
        uint4 s2 = *(const uint4*)&sbf[d * 256 + 128 + u * 8];
        unsigned p1[4] = {s1.x, s1.y, s1.z, s1.w};
        unsigned p2[4] = {s2.x, s2.y, s2.z, s2.w};
        float o[8];
        #pragma unroll
        for (int q = 0; q < 4; ++q) {
            o[q*2+0] = bf2f((unsigned short)(p1[q] & 0xffffu)) + bf2f((unsigned short)(p2[q] & 0xffffu));
            o[q*2+1] = bf2f((unsigned short)(p1[q] >> 16))     + bf2f((unsigned short)(p2[q] >> 16));
        }
        *(float4*)&Ssum[r * 132 + u * 8]     = make_float4(o[0], o[1], o[2], o[3]);
        *(float4*)&Ssum[r * 132 + u * 8 + 4] = make_float4(o[4], o[5], o[6], o[7]);
    }
    __syncthreads();

    int lane = tid & 63, w = tid >> 6;
    int quad = lane >> 4, l15 = lane & 15;
    f32x4 acc[8] = {};
    #pragma unroll 1
    for (int ks = 0; ks < 4; ++ks) {
        bf16x8 a = *(const bf16x8*)&As[(w * 16 + l15) * 136 + ks * 32 + quad * 8];
        #pragma unroll
        for (int t = 0; t < 8; ++t) {
            bf16x8 b = *(const bf16x8*)&wtbf[(t * 16 + l15) * 128 + ks * 32 + quad * 8];
            acc[t] = __builtin_amdgcn_mfma_f32_16x16x32_bf16(a, b, acc[t], 0, 0, 0);
        }
    }

    // epilogue: pre = acc + Ssum + be; gelu; dot waout; 16-lane reduce; leaky -> sev
    #pragma unroll
    for (int reg = 0; reg < 4; ++reg) {
        int r = w * 16 + quad * 4 + reg;
        float partial = 0.0f;
        #pragma unroll
        for (int t = 0; t < 8; ++t) {
            int col = t * 16 + l15;
            float v = acc[t][reg] + Ssum[r * 132 + col] + be_s[col];
            partial += gelu_f(v) * waout_s[col];
        }
        partial += __shfl_xor(partial, 1, 16);
        partial += __shfl_xor(partial, 2, 16);
        partial += __shfl_xor(partial, 4, 16);
        partial += __shfl_xor(partial, 8, 16);
        if (l15 == 0) e_out[e0 + r] = leaky_f(partial + b_aout);
    }
}

// ---------------- final GEMM: rst[N][128] = [neigh, neigh2, feat] @ WT_final + b_final ----------------
__global__ __launch_bounds__(256) void gemm_final(const float* __restrict__ feat,
                                                  float* __restrict__ out,
                                                  float* __restrict__ ws) {
    __shared__ float As[64 * 36];
    __shared__ float Bs[32 * 132];
    int tid = threadIdx.x, tx = tid & 15, ty = tid >> 4;
    int row0 = blockIdx.x * 64;
    const float* WT = ws + OFF_WT_FINAL;
    const float* neigh  = ws + OFF_NEIGH;
    const float* neigh2 = ws + OFF_NEIGH2;
    const float* bfin   = ws + OFF_BFIN;
    float acc[4][8] = {};
    for (int k0 = 0; k0 < 384; k0 += 32) {
        #pragma unroll
        for (int it = 0; it < 2; ++it) {
            int idx = tid + it * 256;
            int r = idx >> 3, kq = idx & 7;
            int rr = min(row0 + r, NN - 1);
            int kg = k0 + kq * 4;
            float4 v;
            if (k0 < 128) {
                v = ((const float4*)neigh)[rr * 32 + (kg >> 2)];
            } else if (k0 < 256) {
                v = ((const float4*)neigh2)[rr * 32 + ((kg - 128) >> 2)];
            } else {
                v = ((const float4*)feat)[rr * 32 + ((kg - 256) >> 2)];
            }
            ((float4*)As)[r * 9 + kq] = v;
        }
        #pragma unroll
        for (int it = 0; it < 4; ++it) {
            int idx = tid + it * 256;
            int kk = idx >> 5, cq = idx & 31;
            float4 v = ((const float4*)WT)[(k0 + kk) * 32 + cq];
            ((float4*)Bs)[kk * 33 + cq] = v;
        }
        __syncthreads();
        #pragma unroll 4
        for (int kk = 0; kk < 32; ++kk) {
            float4 b0 = ((const float4*)Bs)[kk * 33 + tx];
            float4 b1 = ((const float4*)Bs)[kk * 33 + 16 + tx];
            #pragma unroll
            for (int j = 0; j < 4; ++j) {
                float av = As[(ty * 4 + j) * 36 + kk];
                acc[j][0] += av * b0.x; acc[j][1] += av * b0.y;
                acc[j][2] += av * b0.z; acc[j][3] += av * b0.w;
                acc[j][4] += av * b1.x; acc[j][5] += av * b1.y;
                acc[j][6] += av * b1.z; acc[j][7] += av * b1.w;
            }
        }
        __syncthreads();
    }
    #pragma unroll
    for (int j = 0; j < 4; ++j) {
        int row = row0 + ty * 4 + j;
        if (row >= NN) continue;
        #pragma unroll
        for (int g = 0; g < 2; ++g) {
            int c = g * 64 + tx * 4;
            float4 v = make_float4(acc[j][g*4+0] + bfin[c+0], acc[j][g*4+1] + bfin[c+1],
                                   acc[j][g*4+2] + bfin[c+2], acc[j][g*4+3] + bfin[c+3]);
            ((float4*)out)[(row * 128 + c) >> 2] = v;
        }
    }
}

// ---------------- MLP layer ----------------
__global__ __launch_bounds__(256) void gemm_mlp(const float* __restrict__ rst_in,
                                                float* __restrict__ out,
                                                const float* __restrict__ mlp_b,
                                                int layer,
                                                float* __restrict__ ws) {
    __shared__ float As[64 * 36];
    __shared__ float Bs[32 * 132];
    int tid = threadIdx.x, tx = tid & 15, ty = tid >> 4;
    int row0 = blockIdx.x * 64;
    const float* WT = ws + OFF_WT_MLP + layer * 16384;
    const float* bias = mlp_b + layer * 128;
    float acc[4][8] = {};
    for (int k0 = 0; k0 < 128; k0 += 32) {
        #pragma unroll
        for (int it = 0; it < 2; ++it) {
            int idx = tid + it * 256;
            int r = idx >> 3, kq = idx & 7;
            int rr = min(row0 + r, NN - 1);
            float4 v = ((const float4*)rst_in)[rr * 32 + (k0 >> 2) + kq];
            v.x = gelu_f(v.x); v.y = gelu_f(v.y); v.z = gelu_f(v.z); v.w = gelu_f(v.w);
            ((float4*)As)[r * 9 + kq] = v;
        }
        #pragma unroll
        for (int it = 0; it < 4; ++it) {
            int idx = tid + it * 256;
            int kk = idx >> 5, cq = idx & 31;
            float4 v = ((const float4*)WT)[(k0 + kk) * 32 + cq];
            ((float4*)Bs)[kk * 33 + cq] = v;
        }
        __syncthreads();
        #pragma unroll 4
        for (int kk = 0; kk < 32; ++kk) {
            float4 b0 = ((const float4*)Bs)[kk * 33 + tx];
            float4 b1 = ((const float4*)Bs)[kk * 33 + 16 + tx];
            #pragma unroll
            for (int j = 0; j < 4; ++j) {
                float av = As[(ty * 4 + j) * 36 + kk];
                acc[j][0] += av * b0.x; acc[j][1] += av * b0.y;
                acc[j][2] += av * b0.z; acc[j][3] += av * b0.w;
                acc[j][4] += av * b1.x; acc[j][5] += av * b1.y;
                acc[j][6] += av * b1.z; acc[j][7] += av * b1.w;
            }
        }
        __syncthreads();
    }
    #pragma unroll
    for (int j = 0; j < 4; ++j) {
        int row = row0 + ty * 4 + j;
        if (row >= NN) continue;
        #pragma unroll
        for (int g = 0; g < 2; ++g) {
            int c = g * 64 + tx * 4;
            float4 old = ((const float4*)rst_in)[(row * 128 + c) >> 2];
            float4 v = make_float4(old.x + acc[j][g*4+0] + bias[c+0],
                                   old.y + acc[j][g*4+1] + bias[c+1],
                                   old.z + acc[j][g*4+2] + bias[c+2],
                                   old.w + acc[j][g*4+3] + bias[c+3]);
            ((float4*)out)[(row * 128 + c) >> 2] = v;
        }
    }
}

// ---------------- host launch ----------------
extern "C" void kernel_launch(void* const* d_in, const int* in_sizes, int n_in,
                              void* d_out, int out_size, void* d_ws, size_t ws_size,
                              hipStream_t stream) {
    const float* feat = (const float*)d_in[0];
    WnormArgs wa;
    wa.asrc_v = (const float*)d_in[1];  wa.asrc_g = (const float*)d_in[2];  wa.asrc_b = (const float*)d_in[3];
    wa.adst_v = (const float*)d_in[4];  wa.adst_g = (const float*)d_in[5];  wa.adst_b = (const float*)d_in[6];
    wa.asub_v = (const float*)d_in[7];  wa.asub_g = (const float*)d_in[8];  wa.asub_b = (const float*)d_in[9];
    wa.amul_v = (const float*)d_in[10]; wa.amul_g = (const float*)d_in[11]; wa.amul_b = (const float*)d_in[12];
    wa.aout_v = (const float*)d_in[13]; wa.aout_g = (const float*)d_in[14]; wa.aout_b = (const float*)d_in[15];
    wa.pool_v = (const float*)d_in[16]; wa.pool_g = (const float*)d_in[17]; wa.pool_b = (const float*)d_in[18];
    wa.pool2_v= (const float*)d_in[19]; wa.pool2_g= (const float*)d_in[20]; wa.pool2_b= (const float*)d_in[21];
    wa.self_v = (const float*)d_in[22]; wa.self_g = (const float*)d_in[23]; wa.self_b = (const float*)d_in[24];
    wa.neigh_v= (const float*)d_in[25]; wa.neigh_g= (const float*)d_in[26]; wa.neigh_b= (const float*)d_in[27];
    wa.neigh2_v=(const float*)d_in[28]; wa.neigh2_g=(const float*)d_in[29]; wa.neigh2_b=(const float*)d_in[30];
    wa.mlp_v  = (const float*)d_in[31]; wa.mlp_g  = (const float*)d_in[32]; wa.mlp_b  = (const float*)d_in[33];
    const int* src = (const int*)d_in[34];
    const int* dst = (const int*)d_in[35];
    float* out = (float*)d_out;
    float* ws = (float*)d_ws;
    wa.ws = ws;
    unsigned short* featbf = (unsigned short*)(ws + OFF_NEIGH);
    unsigned short* wtbf   = (unsigned short*)(ws + OFF_NEIGH + 3300000);
    unsigned short* sbf    = (unsigned short*)(ws + OFF_NEIGH2);
    unsigned short* hbf    = (unsigned short*)(ws + OFF_HBF);

    // 1) normalized weights + fused bias vectors
    wnorm_kernel<<<dim3(1281), dim3(128), 0, stream>>>(wa);
    // 2) bf16 conversions
    convert_feat_kernel<<<dim3(NN * 128 / (256 * 8)), dim3(256), 0, stream>>>(feat, featbf);
    convert_wt_kernel<<<dim3(64), dim3(256), 0, stream>>>(ws, wtbf);
    // 3) CSR-by-dst (src+dst only -> runs before edge GEMM)
    hist_zero_kernel<<<dim3((NN + 255) / 256), dim3(256), 0, stream>>>(ws);
    hist_kernel<<<dim3((EE + 255) / 256), dim3(256), 0, stream>>>(dst, ws);
    scan_kernel<<<dim3(1), dim3(1024), 0, stream>>>(ws);
    scatteridx_kernel<<<dim3((EE + 255) / 256), dim3(256), 0, stream>>>(src, dst, ws);
    // 4) node-level GEMM: S table (bf16) + h/h2 (bf16)
    gemm_node<<<dim3(782, 4), dim3(256), 0, stream>>>(feat, wa.pool_b, wa.pool2_b, sbf, hbf, ws);
    // 5) edge GEMM (MFMA bf16, dst-sorted order) -> sev
    gemm_edge<<<dim3(EE / 64), dim3(256), 0, stream>>>(featbf, wtbf, sbf, ws);
    // 6) segmented reduce -> neigh (max, zeroed), neigh2 (mean)
    //    (overwrites featbf/wtbf/sbf alias regions — safe, gemm_edge is done)
    segreduce_kernel<<<dim3(NN / 4), dim3(256), 0, stream>>>(ws);
    // 7) final fused GEMM -> rst (d_out)
    gemm_final<<<dim3(782), dim3(256), 0, stream>>>(feat, out, ws);
    // 8) two residual MLP layers (in-place, row-wise safe)
    gemm_mlp<<<dim3(782), dim3(256), 0, stream>>>(out, out, wa.mlp_b, 0, ws);
    gemm_mlp<<<dim3(782), dim3(256), 0, stream>>>(out, out, wa.mlp_b, 1, ws);
}

// Round 6
// 841.560 us; speedup vs baseline: 3.0593x; 1.1205x over previous
//
#include <hip/hip_runtime.h>
#include <math.h>

// ---------------- problem constants ----------------
constexpr int NN = 50000;   // nodes
constexpr int EE = 800000;  // edges

// ---------------- workspace layout (float offsets) ----------------
// f32 weights (written by wnorm)
constexpr int OFF_WT_NODE  = 0;        // [128][512] k-major: col groups 0:asrc+asub 1:adst-asub 2:pool 3:pool2
constexpr int OFF_WT_AMUL  = 65536;    // [128][128] k-major
constexpr int OFF_WT_FINAL = 81920;    // [384][128] k-major; k: 0-127 neigh, 128-255 neigh2, 256-383 self
constexpr int OFF_WT_MLP   = 131072;   // 2 x [128][128] k-major
constexpr int OFF_WAOUT    = 163840;   // [128]
constexpr int OFF_BE       = 163968;   // [128]
constexpr int OFF_BFIN     = 164096;   // [128]
constexpr int OFF_BAOUT    = 164224;   // [1] (pad 16)
// bf16 transposed weight tables ([o][k])
constexpr int OFF_WNODEBF  = 164240;               // 512*128 ushort = 32768 fl
constexpr int OFF_WFINBF   = OFF_WNODEBF + 32768;  // 128*384 ushort = 24576 fl
constexpr int OFF_WMLPBF   = OFF_WFINBF + 24576;   // 2*128*128 ushort = 16384 fl
constexpr int OFF_WAMULBF  = OFF_WMLPBF + 16384;   // 128*128 ushort = 8192 fl
// big arrays
constexpr int OFF_FEATBF   = OFF_WAMULBF + 8192;   // [N][128] bf16
constexpr int OFF_SBF      = OFF_FEATBF + NN*64;   // [N][256] bf16 (S_src | S_dst)
constexpr int OFF_HBF      = OFF_SBF + NN*128;     // [N][256] bf16 (h | h2)
constexpr int OFF_SEV      = OFF_HBF + NN*128;     // [E] f32, dst-sorted e
constexpr int OFF_NEIGHBF  = OFF_SEV + EE;         // [N][256] bf16 (neigh | neigh2)
constexpr int OFF_STARTS   = OFF_NEIGHBF + NN*128; // [N+1] int (+pad)
constexpr int OFF_HIST     = OFF_STARTS + NN + 8;  // [N] int
constexpr int OFF_CURSOR   = OFF_HIST + NN;        // [N] int
constexpr int OFF_SSRCD    = OFF_CURSOR + NN;      // [E] int2 (src,dst sorted by dst)

typedef __attribute__((ext_vector_type(8))) short bf16x8;
typedef __attribute__((ext_vector_type(4))) float f32x4;

// ---------------- device helpers ----------------
__device__ __forceinline__ float gelu_f(float x) {
    return 0.5f * x * (1.0f + erff(x * 0.70710678118654752440f));
}
__device__ __forceinline__ float leaky_f(float x) {
    return x > 0.0f ? x : 0.2f * x;
}
__device__ __forceinline__ unsigned short f2bf(float x) {
    unsigned u = __float_as_uint(x);
    return (unsigned short)((u + 0x7fffu + ((u >> 16) & 1u)) >> 16);
}
__device__ __forceinline__ float bf2f(unsigned short b) {
    return __uint_as_float(((unsigned)b) << 16);
}
__device__ __forceinline__ unsigned mulpack(unsigned a, unsigned b) {
    float a0 = __uint_as_float(a << 16), a1 = __uint_as_float(a & 0xffff0000u);
    float b0 = __uint_as_float(b << 16), b1 = __uint_as_float(b & 0xffff0000u);
    return (unsigned)f2bf(a0 * b0) | ((unsigned)f2bf(a1 * b1) << 16);
}
__device__ __forceinline__ unsigned addpack(unsigned a, unsigned b) {
    float a0 = __uint_as_float(a << 16), a1 = __uint_as_float(a & 0xffff0000u);
    float b0 = __uint_as_float(b << 16), b1 = __uint_as_float(b & 0xffff0000u);
    return (unsigned)f2bf(a0 + b0) | ((unsigned)f2bf(a1 + b1) << 16);
}
__device__ __forceinline__ float block_sum128(float v, float* sbuf) {
    #pragma unroll
    for (int o = 32; o > 0; o >>= 1) v += __shfl_down(v, o, 64);
    int lane = threadIdx.x & 63, w = threadIdx.x >> 6;
    if (lane == 0) sbuf[w] = v;
    __syncthreads();
    float r = sbuf[0] + sbuf[1];
    __syncthreads();
    return r;
}

// ---------------- weight normalization ----------------
struct WnormArgs {
    const float *asrc_v, *asrc_g, *asrc_b;
    const float *adst_v, *adst_g, *adst_b;
    const float *asub_v, *asub_g, *asub_b;
    const float *amul_v, *amul_g, *amul_b;
    const float *aout_v, *aout_g, *aout_b;
    const float *pool_v, *pool_g, *pool_b;
    const float *pool2_v, *pool2_g, *pool2_b;
    const float *self_v, *self_g, *self_b;
    const float *neigh_v, *neigh_g, *neigh_b;
    const float *neigh2_v, *neigh2_g, *neigh2_b;
    const float *mlp_v, *mlp_g, *mlp_b;
    float* ws;
};

__global__ __launch_bounds__(128) void wnorm_kernel(WnormArgs a) {
    __shared__ float sbuf[2];
    int bid = blockIdx.x, i = threadIdx.x;
    float* ws = a.ws;
    if (bid < 1280) {
        int o = bid & 127, grp = bid >> 7;
        const float *v1 = nullptr, *g1 = nullptr, *v2 = nullptr, *g2 = nullptr;
        float sgn2 = 1.0f; float* dst = nullptr; int stride = 0;
        switch (grp) {
            case 0: v1=a.asrc_v; g1=a.asrc_g; v2=a.asub_v; g2=a.asub_g; sgn2= 1.f; dst=ws+OFF_WT_NODE+o;        stride=512; break;
            case 1: v1=a.adst_v; g1=a.adst_g; v2=a.asub_v; g2=a.asub_g; sgn2=-1.f; dst=ws+OFF_WT_NODE+128+o;    stride=512; break;
            case 2: v1=a.pool_v;  g1=a.pool_g;  dst=ws+OFF_WT_NODE+256+o;          stride=512; break;
            case 3: v1=a.pool2_v; g1=a.pool2_g; dst=ws+OFF_WT_NODE+384+o;          stride=512; break;
            case 4: v1=a.amul_v;  g1=a.amul_g;  dst=ws+OFF_WT_AMUL+o;              stride=128; break;
            case 5: v1=a.neigh_v; g1=a.neigh_g; dst=ws+OFF_WT_FINAL+o;             stride=128; break;
            case 6: v1=a.neigh2_v;g1=a.neigh2_g;dst=ws+OFF_WT_FINAL+128*128+o;     stride=128; break;
            case 7: v1=a.self_v;  g1=a.self_g;  dst=ws+OFF_WT_FINAL+256*128+o;     stride=128; break;
            case 8: v1=a.mlp_v;        g1=a.mlp_g;     dst=ws+OFF_WT_MLP+o;        stride=128; break;
            case 9: v1=a.mlp_v+16384;  g1=a.mlp_g+128; dst=ws+OFF_WT_MLP+16384+o;  stride=128; break;
        }
        float x1 = v1[o*128 + i];
        float n1 = sqrtf(block_sum128(x1*x1, sbuf));
        float w = g1[o] * x1 / n1;
        if (v2) {
            float x2 = v2[o*128 + i];
            float n2 = sqrtf(block_sum128(x2*x2, sbuf));
            w += sgn2 * g2[o] * x2 / n2;
        }
        dst[i * stride] = w;
    } else {
        float v = a.aout_v[i];
        float n = sqrtf(block_sum128(v*v, sbuf));
        ws[OFF_WAOUT + i] = a.aout_g[0] * v / n;
        ws[OFF_BE + i]    = a.asrc_b[i] + a.adst_b[i] + a.asub_b[i] + a.amul_b[i];
        ws[OFF_BFIN + i]  = a.self_b[i] + a.neigh_b[i] + a.neigh2_b[i];
        if (i == 0) ws[OFF_BAOUT] = a.aout_b[0];
    }
}

// ---------------- bf16 conversions ----------------
__global__ __launch_bounds__(256) void convert_feat_kernel(const float* __restrict__ feat,
                                                           unsigned short* __restrict__ featbf) {
    int i = (blockIdx.x * 256 + threadIdx.x) * 8;
    float4 v0 = ((const float4*)feat)[i >> 2];
    float4 v1 = ((const float4*)feat)[(i >> 2) + 1];
    uint4 p;
    p.x = (unsigned)f2bf(v0.x) | ((unsigned)f2bf(v0.y) << 16);
    p.y = (unsigned)f2bf(v0.z) | ((unsigned)f2bf(v0.w) << 16);
    p.z = (unsigned)f2bf(v1.x) | ((unsigned)f2bf(v1.y) << 16);
    p.w = (unsigned)f2bf(v1.z) | ((unsigned)f2bf(v1.w) << 16);
    *(uint4*)&featbf[i] = p;
}

// all weight tables -> transposed bf16 [o][k]; 640 blocks x 256
__global__ __launch_bounds__(256) void convert_weights_kernel(float* __restrict__ ws) {
    int idx = blockIdx.x * 256 + threadIdx.x;
    unsigned short* wnodebf = (unsigned short*)(ws + OFF_WNODEBF);
    unsigned short* wfinbf  = (unsigned short*)(ws + OFF_WFINBF);
    unsigned short* wmlpbf  = (unsigned short*)(ws + OFF_WMLPBF);
    unsigned short* wamulbf = (unsigned short*)(ws + OFF_WAMULBF);
    if (idx < 65536) {                 // node: [k 128][n 512] -> [n][k]
        int k = idx >> 9, n = idx & 511;
        wnodebf[n * 128 + k] = f2bf(ws[OFF_WT_NODE + k * 512 + n]);
    } else if (idx < 114688) {         // final: [k 384][o 128] -> [o][k]
        int i = idx - 65536, k = i >> 7, o = i & 127;
        wfinbf[o * 384 + k] = f2bf(ws[OFF_WT_FINAL + k * 128 + o]);
    } else if (idx < 147456) {         // mlp: 2 x [k 128][o 128] -> [o][k]
        int i = idx - 114688, l = i >> 14, j = i & 16383, k = j >> 7, o = j & 127;
        wmlpbf[l * 16384 + o * 128 + k] = f2bf(ws[OFF_WT_MLP + l * 16384 + k * 128 + o]);
    } else {                           // amul: [k 128][o 128] -> [o][k]
        int i = idx - 147456, k = i >> 7, o = i & 127;
        wamulbf[o * 128 + k] = f2bf(ws[OFF_WT_AMUL + k * 128 + o]);
    }
}

// ---------------- CSR-by-dst construction ----------------
__global__ __launch_bounds__(256) void hist_zero_kernel(float* __restrict__ ws) {
    int i = blockIdx.x * 256 + threadIdx.x;
    if (i < NN) ((int*)(ws + OFF_HIST))[i] = 0;
}

__global__ __launch_bounds__(256) void hist_kernel(const int* __restrict__ dst, float* __restrict__ ws) {
    int e = blockIdx.x * 256 + threadIdx.x;
    if (e < EE) atomicAdd(&((int*)(ws + OFF_HIST))[dst[e]], 1);
}

__global__ __launch_bounds__(1024) void scan_kernel(float* __restrict__ ws) {
    __shared__ int sp[1024];
    const int* hist = (const int*)(ws + OFF_HIST);
    int* starts = (int*)(ws + OFF_STARTS);
    int* cursor = (int*)(ws + OFF_CURSOR);
    int t = threadIdx.x;
    const int C = 49;
    int base = t * C;
    int local = 0;
    for (int j = 0; j < C; ++j) { int idx = base + j; if (idx < NN) local += hist[idx]; }
    sp[t] = local;
    __syncthreads();
    for (int o = 1; o < 1024; o <<= 1) {
        int v = (t >= o) ? sp[t - o] : 0;
        __syncthreads();
        sp[t] += v;
        __syncthreads();
    }
    int run = sp[t] - local;
    for (int j = 0; j < C; ++j) {
        int idx = base + j;
        if (idx < NN) { starts[idx] = run; cursor[idx] = run; run += hist[idx]; }
    }
    if (t == 0) starts[NN] = EE;
}

__global__ __launch_bounds__(256) void scatteridx_kernel(const int* __restrict__ src,
                                                         const int* __restrict__ dst,
                                                         float* __restrict__ ws) {
    int e = blockIdx.x * 256 + threadIdx.x;
    if (e >= EE) return;
    int d = dst[e];
    int pos = atomicAdd(&((int*)(ws + OFF_CURSOR))[d], 1);
    ((int2*)(ws + OFF_SSRCD))[pos] = make_int2(src[e], d);
}

// ---------------- segmented reduction -> neighbf bf16 [N][256] ----------------
__global__ __launch_bounds__(256) void segreduce_kernel(float* __restrict__ ws) {
    int n = blockIdx.x * 4 + (threadIdx.x >> 6);
    int lane = threadIdx.x & 63;
    const int* starts = (const int*)(ws + OFF_STARTS);
    const int2* ssrcd = (const int2*)(ws + OFF_SSRCD);
    const float* sev = ws + OFF_SEV;
    const unsigned short* hbf = (const unsigned short*)(ws + OFF_HBF);
    unsigned short* neighbf = (unsigned short*)(ws + OFF_NEIGHBF);
    int s0 = starts[n], s1 = starts[n + 1];
    float2 mx = make_float2(-INFINITY, -INFINITY);
    float2 sm = make_float2(0.f, 0.f);
    for (int i = s0; i < s1; ++i) {
        int s = ssrcd[i].x;
        float ev = sev[i];
        unsigned hv  = *(const unsigned*)&hbf[s * 256 + lane * 2];
        unsigned h2v = *(const unsigned*)&hbf[s * 256 + 128 + lane * 2];
        float hx = bf2f((unsigned short)(hv & 0xffffu)),  hy = bf2f((unsigned short)(hv >> 16));
        float gx = bf2f((unsigned short)(h2v & 0xffffu)), gy = bf2f((unsigned short)(h2v >> 16));
        mx.x = fmaxf(mx.x, ev * hx); mx.y = fmaxf(mx.y, ev * hy);
        sm.x += ev * gx;             sm.y += ev * gy;
    }
    int cnt = s1 - s0;
    if (cnt == 0) { mx.x = 0.f; mx.y = 0.f; }
    float ic = 1.0f / (float)max(cnt, 1);
    *(unsigned*)&neighbf[n * 256 + lane * 2] =
        (unsigned)f2bf(mx.x) | ((unsigned)f2bf(mx.y) << 16);
    *(unsigned*)&neighbf[n * 256 + 128 + lane * 2] =
        (unsigned)f2bf(sm.x * ic) | ((unsigned)f2bf(sm.y * ic) << 16);
}

// ---------------- node GEMM (MFMA): 64 rows x 128 cols per block, gy = col group ----------------
__global__ __launch_bounds__(256) void gemm_node_mfma(const unsigned short* __restrict__ featbf,
                                                      const float* __restrict__ pool_b,
                                                      const float* __restrict__ pool2_b,
                                                      unsigned short* __restrict__ sbf,
                                                      unsigned short* __restrict__ hbf,
                                                      const unsigned short* __restrict__ wnodebf) {
    __shared__ unsigned short As[64 * 136];
    int tid = threadIdx.x;
    int row0 = blockIdx.x * 64, gy = blockIdx.y;
    #pragma unroll
    for (int it = 0; it < 4; ++it) {
        int idx = tid + it * 256;
        int r = idx >> 4, u = idx & 15;
        int rr = min(row0 + r, NN - 1);
        *(uint4*)&As[r * 136 + u * 8] = *(const uint4*)&featbf[rr * 128 + u * 8];
    }
    __syncthreads();
    int lane = tid & 63, w = tid >> 6;
    int quad = lane >> 4, l15 = lane & 15;
    const unsigned short* B = wnodebf + gy * 128 * 128;
    f32x4 acc[8] = {};
    #pragma unroll 1
    for (int ks = 0; ks < 4; ++ks) {
        bf16x8 a = *(const bf16x8*)&As[(w * 16 + l15) * 136 + ks * 32 + quad * 8];
        #pragma unroll
        for (int t = 0; t < 8; ++t) {
            bf16x8 b = *(const bf16x8*)&B[(t * 16 + l15) * 128 + ks * 32 + quad * 8];
            acc[t] = __builtin_amdgcn_mfma_f32_16x16x32_bf16(a, b, acc[t], 0, 0, 0);
        }
    }
    #pragma unroll
    for (int reg = 0; reg < 4; ++reg) {
        int row = row0 + w * 16 + quad * 4 + reg;
        if (row >= NN) continue;
        #pragma unroll
        for (int t = 0; t < 8; ++t) {
            int col = t * 16 + l15;
            float v = acc[t][reg];
            if (gy == 0)      sbf[row * 256 + col]       = f2bf(v);
            else if (gy == 1) sbf[row * 256 + 128 + col] = f2bf(v);
            else if (gy == 2) hbf[row * 256 + col]       = f2bf(gelu_f(v + pool_b[col]));
            else              hbf[row * 256 + 128 + col] = f2bf(gelu_f(v + pool2_b[col]));
        }
    }
}

// ---------------- edge GEMM (bf16 MFMA, dst-sorted) + fused epilogue -> sev ----------------
__global__ __launch_bounds__(256) void gemm_edge(const unsigned short* __restrict__ featbf,
                                                 const unsigned short* __restrict__ wamulbf,
                                                 const unsigned short* __restrict__ sbf,
                                                 float* __restrict__ ws) {
    __shared__ unsigned short As[64 * 136];
    __shared__ unsigned short Sbf[64 * 136];
    __shared__ int sI[64], dI[64];
    __shared__ float waout_s[128], be_s[128];
    int tid = threadIdx.x;
    int e0 = blockIdx.x * 64;
    const int2* ssrcd = (const int2*)(ws + OFF_SSRCD);
    if (tid < 64) { int2 v = ssrcd[e0 + tid]; sI[tid] = v.x; dI[tid] = v.y; }
    else if (tid < 192) { int i = tid - 64; waout_s[i] = ws[OFF_WAOUT + i]; be_s[i] = ws[OFF_BE + i]; }
    float b_aout = ws[OFF_BAOUT];
    float* e_out = ws + OFF_SEV;
    __syncthreads();

    #pragma unroll
    for (int it = 0; it < 4; ++it) {
        int idx = tid + it * 256;
        int r = idx >> 4, u = idx & 15;
        int s = sI[r], d = dI[r];
        uint4 av = *(const uint4*)&featbf[s * 128 + u * 8];
        uint4 bv = *(const uint4*)&featbf[d * 128 + u * 8];
        uint4 m;
        m.x = mulpack(av.x, bv.x); m.y = mulpack(av.y, bv.y);
        m.z = mulpack(av.z, bv.z); m.w = mulpack(av.w, bv.w);
        *(uint4*)&As[r * 136 + u * 8] = m;
        uint4 s1 = *(const uint4*)&sbf[s * 256 + u * 8];
        uint4 s2 = *(const uint4*)&sbf[d * 256 + 128 + u * 8];
        uint4 sm;
        sm.x = addpack(s1.x, s2.x); sm.y = addpack(s1.y, s2.y);
        sm.z = addpack(s1.z, s2.z); sm.w = addpack(s1.w, s2.w);
        *(uint4*)&Sbf[r * 136 + u * 8] = sm;
    }
    __syncthreads();

    int lane = tid & 63, w = tid >> 6;
    int quad = lane >> 4, l15 = lane & 15;
    f32x4 acc[8] = {};
    #pragma unroll 1
    for (int ks = 0; ks < 4; ++ks) {
        bf16x8 a = *(const bf16x8*)&As[(w * 16 + l15) * 136 + ks * 32 + quad * 8];
        #pragma unroll
        for (int t = 0; t < 8; ++t) {
            bf16x8 b = *(const bf16x8*)&wamulbf[(t * 16 + l15) * 128 + ks * 32 + quad * 8];
            acc[t] = __builtin_amdgcn_mfma_f32_16x16x32_bf16(a, b, acc[t], 0, 0, 0);
        }
    }

    #pragma unroll
    for (int reg = 0; reg < 4; ++reg) {
        int r = w * 16 + quad * 4 + reg;
        float partial = 0.0f;
        #pragma unroll
        for (int t = 0; t < 8; ++t) {
            int col = t * 16 + l15;
            float v = acc[t][reg] + bf2f(Sbf[r * 136 + col]) + be_s[col];
            partial += gelu_f(v) * waout_s[col];
        }
        partial += __shfl_xor(partial, 1, 16);
        partial += __shfl_xor(partial, 2, 16);
        partial += __shfl_xor(partial, 4, 16);
        partial += __shfl_xor(partial, 8, 16);
        if (l15 == 0) e_out[e0 + r] = leaky_f(partial + b_aout);
    }
}

// ---------------- final GEMM (MFMA, K=384, single-stage LDS) -> out f32 ----------------
__global__ __launch_bounds__(256) void gemm_final_mfma(const unsigned short* __restrict__ neighbf,
                                                       const unsigned short* __restrict__ featbf,
                                                       const unsigned short* __restrict__ wfinbf,
                                                       float* __restrict__ out,
                                                       const float* __restrict__ ws) {
    __shared__ unsigned short As[64 * 392];   // 64 rows x 384 cols bf16 (+8 pad)
    __shared__ float bfin_s[128];
    int tid = threadIdx.x;
    int row0 = blockIdx.x * 64;
    if (tid < 128) bfin_s[tid] = ws[OFF_BFIN + tid];
    #pragma unroll
    for (int rg = 0; rg < 3; ++rg) {
        #pragma unroll
        for (int it = 0; it < 4; ++it) {
            int idx = tid + it * 256;
            int r = idx >> 4, u = idx & 15;
            int rr = min(row0 + r, NN - 1);
            const unsigned short* sp = (rg == 0) ? &neighbf[rr * 256 + u * 8]
                                     : (rg == 1) ? &neighbf[rr * 256 + 128 + u * 8]
                                                 : &featbf[rr * 128 + u * 8];
            *(uint4*)&As[r * 392 + rg * 128 + u * 8] = *(const uint4*)sp;
        }
    }
    __syncthreads();
    int lane = tid & 63, w = tid >> 6;
    int quad = lane >> 4, l15 = lane & 15;
    f32x4 acc[8] = {};
    #pragma unroll 1
    for (int ks = 0; ks < 12; ++ks) {
        bf16x8 a = *(const bf16x8*)&As[(w * 16 + l15) * 392 + ks * 32 + quad * 8];
        #pragma unroll
        for (int t = 0; t < 8; ++t) {
            bf16x8 b = *(const bf16x8*)&wfinbf[(t * 16 + l15) * 384 + ks * 32 + quad * 8];
            acc[t] = __builtin_amdgcn_mfma_f32_16x16x32_bf16(a, b, acc[t], 0, 0, 0);
        }
    }
    #pragma unroll
    for (int reg = 0; reg < 4; ++reg) {
        int row = row0 + w * 16 + quad * 4 + reg;
        if (row >= NN) continue;
        #pragma unroll
        for (int t = 0; t < 8; ++t) {
            int col = t * 16 + l15;
            out[row * 128 + col] = acc[t][reg] + bfin_s[col];
        }
    }
}

// ---------------- MLP layer (MFMA, in-place on out; block reads only its own rows) ----------------
__global__ __launch_bounds__(256) void gemm_mlp_mfma(float* __restrict__ out,
                                                     const unsigned short* __restrict__ wmlp,
                                                     const float* __restrict__ bias) {
    __shared__ unsigned short As[64 * 136];
    int tid = threadIdx.x;
    int row0 = blockIdx.x * 64;
    #pragma unroll
    for (int it = 0; it < 8; ++it) {
        int idx = tid + it * 256;            // 64 rows x 32 float4-units
        int r = idx >> 5, u = idx & 31;
        int rr = min(row0 + r, NN - 1);      // clamp stays within this block's rows
        float4 v = ((const float4*)out)[rr * 32 + u];
        ushort4 p = make_ushort4(f2bf(gelu_f(v.x)), f2bf(gelu_f(v.y)),
                                 f2bf(gelu_f(v.z)), f2bf(gelu_f(v.w)));
        *(ushort4*)&As[r * 136 + u * 4] = p;
    }
    __syncthreads();
    int lane = tid & 63, w = tid >> 6;
    int quad = lane >> 4, l15 = lane & 15;
    f32x4 acc[8] = {};
    #pragma unroll 1
    for (int ks = 0; ks < 4; ++ks) {
        bf16x8 a = *(const bf16x8*)&As[(w * 16 + l15) * 136 + ks * 32 + quad * 8];
        #pragma unroll
        for (int t = 0; t < 8; ++t) {
            bf16x8 b = *(const bf16x8*)&wmlp[(t * 16 + l15) * 128 + ks * 32 + quad * 8];
            acc[t] = __builtin_amdgcn_mfma_f32_16x16x32_bf16(a, b, acc[t], 0, 0, 0);
        }
    }
    #pragma unroll
    for (int reg = 0; reg < 4; ++reg) {
        int row = row0 + w * 16 + quad * 4 + reg;
        if (row >= NN) continue;
        #pragma unroll
        for (int t = 0; t < 8; ++t) {
            int col = t * 16 + l15;
            out[row * 128 + col] += acc[t][reg] + bias[col];
        }
    }
}

// ---------------- host launch ----------------
extern "C" void kernel_launch(void* const* d_in, const int* in_sizes, int n_in,
                              void* d_out, int out_size, void* d_ws, size_t ws_size,
                              hipStream_t stream) {
    const float* feat = (const float*)d_in[0];
    WnormArgs wa;
    wa.asrc_v = (const float*)d_in[1];  wa.asrc_g = (const float*)d_in[2];  wa.asrc_b = (const float*)d_in[3];
    wa.adst_v = (const float*)d_in[4];  wa.adst_g = (const float*)d_in[5];  wa.adst_b = (const float*)d_in[6];
    wa.asub_v = (const float*)d_in[7];  wa.asub_g = (const float*)d_in[8];  wa.asub_b = (const float*)d_in[9];
    wa.amul_v = (const float*)d_in[10]; wa.amul_g = (const float*)d_in[11]; wa.amul_b = (const float*)d_in[12];
    wa.aout_v = (const float*)d_in[13]; wa.aout_g = (const float*)d_in[14]; wa.aout_b = (const float*)d_in[15];
    wa.pool_v = (const float*)d_in[16]; wa.pool_g = (const float*)d_in[17]; wa.pool_b = (const float*)d_in[18];
    wa.pool2_v= (const float*)d_in[19]; wa.pool2_g= (const float*)d_in[20]; wa.pool2_b= (const float*)d_in[21];
    wa.self_v = (const float*)d_in[22]; wa.self_g = (const float*)d_in[23]; wa.self_b = (const float*)d_in[24];
    wa.neigh_v= (const float*)d_in[25]; wa.neigh_g= (const float*)d_in[26]; wa.neigh_b= (const float*)d_in[27];
    wa.neigh2_v=(const float*)d_in[28]; wa.neigh2_g=(const float*)d_in[29]; wa.neigh2_b=(const float*)d_in[30];
    wa.mlp_v  = (const float*)d_in[31]; wa.mlp_g  = (const float*)d_in[32]; wa.mlp_b  = (const float*)d_in[33];
    const int* src = (const int*)d_in[34];
    const int* dst = (const int*)d_in[35];
    float* out = (float*)d_out;
    float* ws = (float*)d_ws;
    wa.ws = ws;
    unsigned short* featbf  = (unsigned short*)(ws + OFF_FEATBF);
    unsigned short* sbf     = (unsigned short*)(ws + OFF_SBF);
    unsigned short* hbf     = (unsigned short*)(ws + OFF_HBF);
    unsigned short* neighbf = (unsigned short*)(ws + OFF_NEIGHBF);
    unsigned short* wnodebf = (unsigned short*)(ws + OFF_WNODEBF);
    unsigned short* wfinbf  = (unsigned short*)(ws + OFF_WFINBF);
    unsigned short* wmlpbf  = (unsigned short*)(ws + OFF_WMLPBF);
    unsigned short* wamulbf = (unsigned short*)(ws + OFF_WAMULBF);

    // 1) normalized weights + fused bias vectors
    wnorm_kernel<<<dim3(1281), dim3(128), 0, stream>>>(wa);
    // 2) bf16 conversions
    convert_feat_kernel<<<dim3(NN * 128 / (256 * 8)), dim3(256), 0, stream>>>(feat, featbf);
    convert_weights_kernel<<<dim3(640), dim3(256), 0, stream>>>(ws);
    // 3) CSR-by-dst
    hist_zero_kernel<<<dim3((NN + 255) / 256), dim3(256), 0, stream>>>(ws);
    hist_kernel<<<dim3((EE + 255) / 256), dim3(256), 0, stream>>>(dst, ws);
    scan_kernel<<<dim3(1), dim3(1024), 0, stream>>>(ws);
    scatteridx_kernel<<<dim3((EE + 255) / 256), dim3(256), 0, stream>>>(src, dst, ws);
    // 4) node-level GEMM (MFMA): S table + h/h2 (all bf16)
    gemm_node_mfma<<<dim3(782, 4), dim3(256), 0, stream>>>(featbf, wa.pool_b, wa.pool2_b, sbf, hbf, wnodebf);
    // 5) edge GEMM (MFMA, dst-sorted) -> sev
    gemm_edge<<<dim3(EE / 64), dim3(256), 0, stream>>>(featbf, wamulbf, sbf, ws);
    // 6) segmented reduce -> neighbf (max zeroed | mean)
    segreduce_kernel<<<dim3(NN / 4), dim3(256), 0, stream>>>(ws);
    // 7) final GEMM (MFMA) -> out f32
    gemm_final_mfma<<<dim3(782), dim3(256), 0, stream>>>(neighbf, featbf, wfinbf, out, ws);
    // 8) two residual MLP layers (MFMA, in-place, block-self-contained rows)
    gemm_mlp_mfma<<<dim3(782), dim3(256), 0, stream>>>(out, wmlpbf, wa.mlp_b);
    gemm_mlp_mfma<<<dim3(782), dim3(256), 0, stream>>>(out, wmlpbf + 16384, wa.mlp_b + 128);
}

// Round 8
// 808.304 us; speedup vs baseline: 3.1852x; 1.0411x over previous
//
#include <hip/hip_runtime.h>
#include <hip/hip_bf16.h>
#include <math.h>

// ---------------- problem constants ----------------
constexpr int NN = 50000;   // nodes
constexpr int EE = 800000;  // edges

// ---------------- workspace layout (float offsets) ----------------
// f32 weights (written by wnorm)
constexpr int OFF_WT_NODE  = 0;        // [128][512] k-major: col groups 0:asrc+asub 1:adst-asub 2:pool 3:pool2
constexpr int OFF_WT_AMUL  = 65536;    // [128][128] k-major
constexpr int OFF_WT_FINAL = 81920;    // [384][128] k-major; k: 0-127 neigh, 128-255 neigh2, 256-383 self
constexpr int OFF_WT_MLP   = 131072;   // 2 x [128][128] k-major
constexpr int OFF_WAOUT    = 163840;   // [128]
constexpr int OFF_BE       = 163968;   // [128]
constexpr int OFF_BFIN     = 164096;   // [128]
constexpr int OFF_BAOUT    = 164224;   // [1] (pad 16)
// bf16 transposed weight tables ([o][k])
constexpr int OFF_WNODEBF  = 164240;               // 512*128 ushort = 32768 fl
constexpr int OFF_WFINBF   = OFF_WNODEBF + 32768;  // 128*384 ushort = 24576 fl
constexpr int OFF_WMLPBF   = OFF_WFINBF + 24576;   // 2*128*128 ushort = 16384 fl
constexpr int OFF_WAMULBF  = OFF_WMLPBF + 16384;   // 128*128 ushort = 8192 fl
// big arrays
constexpr int OFF_FEATBF   = OFF_WAMULBF + 8192;   // [N][128] bf16
constexpr int OFF_SBF      = OFF_FEATBF + NN*64;   // [N][256] bf16 (S_src | S_dst)
constexpr int OFF_HBF      = OFF_SBF + NN*128;     // [N][256] bf16 (h | h2)
constexpr int OFF_SEV      = OFF_HBF + NN*128;     // [E] f32, dst-sorted e
constexpr int OFF_NEIGHBF  = OFF_SEV + EE;         // [N][256] bf16 (neigh | neigh2)
constexpr int OFF_STARTS   = OFF_NEIGHBF + NN*128; // [N+1] int (+pad)
constexpr int OFF_HIST     = OFF_STARTS + NN + 8;  // [N] int
constexpr int OFF_CURSOR   = OFF_HIST + NN;        // [N] int
constexpr int OFF_SSRCD    = OFF_CURSOR + NN;      // [E] int2 (src,dst sorted by dst)

typedef __attribute__((ext_vector_type(8))) short bf16x8;
typedef __attribute__((ext_vector_type(4))) float f32x4;

// ---------------- device helpers ----------------
// fast GELU (tanh form via sigmoid): max |err| vs exact erf-gelu ~3e-4
__device__ __forceinline__ float gelu_f(float x) {
    float x2 = x * x;
    float u = x * (1.5957691216f + 0.07135481283f * x2);  // 2*0.7978845608*(1 + 0.044715 x^2)
    return x / (1.0f + __expf(-u));
}
__device__ __forceinline__ float leaky_f(float x) {
    return x > 0.0f ? x : 0.2f * x;
}
__device__ __forceinline__ unsigned short f2bf(float x) {
    unsigned u = __float_as_uint(x);
    return (unsigned short)((u + 0x7fffu + ((u >> 16) & 1u)) >> 16);
}
__device__ __forceinline__ float bf2f(unsigned short b) {
    return __uint_as_float(((unsigned)b) << 16);
}
// packed 2x f32 -> bf16x2 (lo in bits 0-15) via HIP's HW-backed scalar convert
__device__ __forceinline__ unsigned pk_bf16(float lo, float hi) {
    __hip_bfloat16 l = __float2bfloat16(lo);
    __hip_bfloat16 h = __float2bfloat16(hi);
    unsigned short lu = *reinterpret_cast<unsigned short*>(&l);
    unsigned short hu = *reinterpret_cast<unsigned short*>(&h);
    return (unsigned)lu | ((unsigned)hu << 16);
}
__device__ __forceinline__ unsigned mulpack(unsigned a, unsigned b) {
    float a0 = __uint_as_float(a << 16), a1 = __uint_as_float(a & 0xffff0000u);
    float b0 = __uint_as_float(b << 16), b1 = __uint_as_float(b & 0xffff0000u);
    return pk_bf16(a0 * b0, a1 * b1);
}
__device__ __forceinline__ unsigned addpack(unsigned a, unsigned b) {
    float a0 = __uint_as_float(a << 16), a1 = __uint_as_float(a & 0xffff0000u);
    float b0 = __uint_as_float(b << 16), b1 = __uint_as_float(b & 0xffff0000u);
    return pk_bf16(a0 + b0, a1 + b1);
}
__device__ __forceinline__ float block_sum128(float v, float* sbuf) {
    #pragma unroll
    for (int o = 32; o > 0; o >>= 1) v += __shfl_down(v, o, 64);
    int lane = threadIdx.x & 63, w = threadIdx.x >> 6;
    if (lane == 0) sbuf[w] = v;
    __syncthreads();
    float r = sbuf[0] + sbuf[1];
    __syncthreads();
    return r;
}

// ---------------- weight normalization ----------------
struct WnormArgs {
    const float *asrc_v, *asrc_g, *asrc_b;
    const float *adst_v, *adst_g, *adst_b;
    const float *asub_v, *asub_g, *asub_b;
    const float *amul_v, *amul_g, *amul_b;
    const float *aout_v, *aout_g, *aout_b;
    const float *pool_v, *pool_g, *pool_b;
    const float *pool2_v, *pool2_g, *pool2_b;
    const float *self_v, *self_g, *self_b;
    const float *neigh_v, *neigh_g, *neigh_b;
    const float *neigh2_v, *neigh2_g, *neigh2_b;
    const float *mlp_v, *mlp_g, *mlp_b;
    float* ws;
};

__global__ __launch_bounds__(128) void wnorm_kernel(WnormArgs a) {
    __shared__ float sbuf[2];
    int bid = blockIdx.x, i = threadIdx.x;
    float* ws = a.ws;
    if (bid < 1280) {
        int o = bid & 127, grp = bid >> 7;
        const float *v1 = nullptr, *g1 = nullptr, *v2 = nullptr, *g2 = nullptr;
        float sgn2 = 1.0f; float* dst = nullptr; int stride = 0;
        switch (grp) {
            case 0: v1=a.asrc_v; g1=a.asrc_g; v2=a.asub_v; g2=a.asub_g; sgn2= 1.f; dst=ws+OFF_WT_NODE+o;        stride=512; break;
            case 1: v1=a.adst_v; g1=a.adst_g; v2=a.asub_v; g2=a.asub_g; sgn2=-1.f; dst=ws+OFF_WT_NODE+128+o;    stride=512; break;
            case 2: v1=a.pool_v;  g1=a.pool_g;  dst=ws+OFF_WT_NODE+256+o;          stride=512; break;
            case 3: v1=a.pool2_v; g1=a.pool2_g; dst=ws+OFF_WT_NODE+384+o;          stride=512; break;
            case 4: v1=a.amul_v;  g1=a.amul_g;  dst=ws+OFF_WT_AMUL+o;              stride=128; break;
            case 5: v1=a.neigh_v; g1=a.neigh_g; dst=ws+OFF_WT_FINAL+o;             stride=128; break;
            case 6: v1=a.neigh2_v;g1=a.neigh2_g;dst=ws+OFF_WT_FINAL+128*128+o;     stride=128; break;
            case 7: v1=a.self_v;  g1=a.self_g;  dst=ws+OFF_WT_FINAL+256*128+o;     stride=128; break;
            case 8: v1=a.mlp_v;        g1=a.mlp_g;     dst=ws+OFF_WT_MLP+o;        stride=128; break;
            case 9: v1=a.mlp_v+16384;  g1=a.mlp_g+128; dst=ws+OFF_WT_MLP+16384+o;  stride=128; break;
        }
        float x1 = v1[o*128 + i];
        float n1 = sqrtf(block_sum128(x1*x1, sbuf));
        float w = g1[o] * x1 / n1;
        if (v2) {
            float x2 = v2[o*128 + i];
            float n2 = sqrtf(block_sum128(x2*x2, sbuf));
            w += sgn2 * g2[o] * x2 / n2;
        }
        dst[i * stride] = w;
    } else {
        float v = a.aout_v[i];
        float n = sqrtf(block_sum128(v*v, sbuf));
        ws[OFF_WAOUT + i] = a.aout_g[0] * v / n;
        ws[OFF_BE + i]    = a.asrc_b[i] + a.adst_b[i] + a.asub_b[i] + a.amul_b[i];
        ws[OFF_BFIN + i]  = a.self_b[i] + a.neigh_b[i] + a.neigh2_b[i];
        if (i == 0) ws[OFF_BAOUT] = a.aout_b[0];
    }
}

// ---------------- bf16 conversions ----------------
__global__ __launch_bounds__(256) void convert_feat_kernel(const float* __restrict__ feat,
                                                           unsigned short* __restrict__ featbf) {
    int i = (blockIdx.x * 256 + threadIdx.x) * 8;
    float4 v0 = ((const float4*)feat)[i >> 2];
    float4 v1 = ((const float4*)feat)[(i >> 2) + 1];
    uint4 p;
    p.x = pk_bf16(v0.x, v0.y);
    p.y = pk_bf16(v0.z, v0.w);
    p.z = pk_bf16(v1.x, v1.y);
    p.w = pk_bf16(v1.z, v1.w);
    *(uint4*)&featbf[i] = p;
}

// all weight tables -> transposed bf16 [o][k]; 640 blocks x 256
__global__ __launch_bounds__(256) void convert_weights_kernel(float* __restrict__ ws) {
    int idx = blockIdx.x * 256 + threadIdx.x;
    unsigned short* wnodebf = (unsigned short*)(ws + OFF_WNODEBF);
    unsigned short* wfinbf  = (unsigned short*)(ws + OFF_WFINBF);
    unsigned short* wmlpbf  = (unsigned short*)(ws + OFF_WMLPBF);
    unsigned short* wamulbf = (unsigned short*)(ws + OFF_WAMULBF);
    if (idx < 65536) {                 // node: [k 128][n 512] -> [n][k]
        int k = idx >> 9, n = idx & 511;
        wnodebf[n * 128 + k] = f2bf(ws[OFF_WT_NODE + k * 512 + n]);
    } else if (idx < 114688) {         // final: [k 384][o 128] -> [o][k]
        int i = idx - 65536, k = i >> 7, o = i & 127;
        wfinbf[o * 384 + k] = f2bf(ws[OFF_WT_FINAL + k * 128 + o]);
    } else if (idx < 147456) {         // mlp: 2 x [k 128][o 128] -> [o][k]
        int i = idx - 114688, l = i >> 14, j = i & 16383, k = j >> 7, o = j & 127;
        wmlpbf[l * 16384 + o * 128 + k] = f2bf(ws[OFF_WT_MLP + l * 16384 + k * 128 + o]);
    } else {                           // amul: [k 128][o 128] -> [o][k]
        int i = idx - 147456, k = i >> 7, o = i & 127;
        wamulbf[o * 128 + k] = f2bf(ws[OFF_WT_AMUL + k * 128 + o]);
    }
}

// ---------------- CSR-by-dst construction ----------------
__global__ __launch_bounds__(256) void hist_zero_kernel(float* __restrict__ ws) {
    int i = blockIdx.x * 256 + threadIdx.x;
    if (i < NN) ((int*)(ws + OFF_HIST))[i] = 0;
}

__global__ __launch_bounds__(256) void hist_kernel(const int* __restrict__ dst, float* __restrict__ ws) {
    int e = blockIdx.x * 256 + threadIdx.x;
    if (e < EE) atomicAdd(&((int*)(ws + OFF_HIST))[dst[e]], 1);
}

__global__ __launch_bounds__(1024) void scan_kernel(float* __restrict__ ws) {
    __shared__ int sp[1024];
    const int* hist = (const int*)(ws + OFF_HIST);
    int* starts = (int*)(ws + OFF_STARTS);
    int* cursor = (int*)(ws + OFF_CURSOR);
    int t = threadIdx.x;
    const int C = 49;
    int base = t * C;
    int local = 0;
    for (int j = 0; j < C; ++j) { int idx = base + j; if (idx < NN) local += hist[idx]; }
    sp[t] = local;
    __syncthreads();
    for (int o = 1; o < 1024; o <<= 1) {
        int v = (t >= o) ? sp[t - o] : 0;
        __syncthreads();
        sp[t] += v;
        __syncthreads();
    }
    int run = sp[t] - local;
    for (int j = 0; j < C; ++j) {
        int idx = base + j;
        if (idx < NN) { starts[idx] = run; cursor[idx] = run; run += hist[idx]; }
    }
    if (t == 0) starts[NN] = EE;
}

__global__ __launch_bounds__(256) void scatteridx_kernel(const int* __restrict__ src,
                                                         const int* __restrict__ dst,
                                                         float* __restrict__ ws) {
    int e = blockIdx.x * 256 + threadIdx.x;
    if (e >= EE) return;
    int d = dst[e];
    int pos = atomicAdd(&((int*)(ws + OFF_CURSOR))[d], 1);
    ((int2*)(ws + OFF_SSRCD))[pos] = make_int2(src[e], d);
}

// ---------------- segmented reduction -> neighbf bf16 [N][256], 2-deep pipelined ----------------
__global__ __launch_bounds__(256) void segreduce_kernel(float* __restrict__ ws) {
    int n = blockIdx.x * 4 + (threadIdx.x >> 6);
    int lane = threadIdx.x & 63;
    const int* starts = (const int*)(ws + OFF_STARTS);
    const int2* ssrcd = (const int2*)(ws + OFF_SSRCD);
    const float* sev = ws + OFF_SEV;
    const unsigned short* hbf = (const unsigned short*)(ws + OFF_HBF);
    unsigned short* neighbf = (unsigned short*)(ws + OFF_NEIGHBF);
    int s0 = starts[n], s1 = starts[n + 1];
    float2 mx = make_float2(-INFINITY, -INFINITY);
    float2 sm = make_float2(0.f, 0.f);
    int i = s0;
    for (; i + 2 <= s1; i += 2) {
        int sA = ssrcd[i].x, sB = ssrcd[i + 1].x;
        float evA = sev[i], evB = sev[i + 1];
        unsigned hvA  = *(const unsigned*)&hbf[sA * 256 + lane * 2];
        unsigned h2vA = *(const unsigned*)&hbf[sA * 256 + 128 + lane * 2];
        unsigned hvB  = *(const unsigned*)&hbf[sB * 256 + lane * 2];
        unsigned h2vB = *(const unsigned*)&hbf[sB * 256 + 128 + lane * 2];
        mx.x = fmaxf(mx.x, evA * bf2f((unsigned short)(hvA & 0xffffu)));
        mx.y = fmaxf(mx.y, evA * bf2f((unsigned short)(hvA >> 16)));
        sm.x += evA * bf2f((unsigned short)(h2vA & 0xffffu));
        sm.y += evA * bf2f((unsigned short)(h2vA >> 16));
        mx.x = fmaxf(mx.x, evB * bf2f((unsigned short)(hvB & 0xffffu)));
        mx.y = fmaxf(mx.y, evB * bf2f((unsigned short)(hvB >> 16)));
        sm.x += evB * bf2f((unsigned short)(h2vB & 0xffffu));
        sm.y += evB * bf2f((unsigned short)(h2vB >> 16));
    }
    if (i < s1) {
        int s = ssrcd[i].x;
        float ev = sev[i];
        unsigned hv  = *(const unsigned*)&hbf[s * 256 + lane * 2];
        unsigned h2v = *(const unsigned*)&hbf[s * 256 + 128 + lane * 2];
        mx.x = fmaxf(mx.x, ev * bf2f((unsigned short)(hv & 0xffffu)));
        mx.y = fmaxf(mx.y, ev * bf2f((unsigned short)(hv >> 16)));
        sm.x += ev * bf2f((unsigned short)(h2v & 0xffffu));
        sm.y += ev * bf2f((unsigned short)(h2v >> 16));
    }
    int cnt = s1 - s0;
    if (cnt == 0) { mx.x = 0.f; mx.y = 0.f; }
    float ic = 1.0f / (float)max(cnt, 1);
    *(unsigned*)&neighbf[n * 256 + lane * 2] = pk_bf16(mx.x, mx.y);
    *(unsigned*)&neighbf[n * 256 + 128 + lane * 2] = pk_bf16(sm.x * ic, sm.y * ic);
}

// ---------------- node GEMM (MFMA): 64 rows x 128 cols per block, gy = col group ----------------
__global__ __launch_bounds__(256) void gemm_node_mfma(const unsigned short* __restrict__ featbf,
                                                      const float* __restrict__ pool_b,
                                                      const float* __restrict__ pool2_b,
                                                      unsigned short* __restrict__ sbf,
                                                      unsigned short* __restrict__ hbf,
                                                      const unsigned short* __restrict__ wnodebf) {
    __shared__ unsigned short As[64 * 136];
    int tid = threadIdx.x;
    int row0 = blockIdx.x * 64, gy = blockIdx.y;
    #pragma unroll
    for (int it = 0; it < 4; ++it) {
        int idx = tid + it * 256;
        int r = idx >> 4, u = idx & 15;
        int rr = min(row0 + r, NN - 1);
        *(uint4*)&As[r * 136 + u * 8] = *(const uint4*)&featbf[rr * 128 + u * 8];
    }
    __syncthreads();
    int lane = tid & 63, w = tid >> 6;
    int quad = lane >> 4, l15 = lane & 15;
    const unsigned short* B = wnodebf + gy * 128 * 128;
    f32x4 acc[8] = {};
    #pragma unroll 1
    for (int ks = 0; ks < 4; ++ks) {
        bf16x8 a = *(const bf16x8*)&As[(w * 16 + l15) * 136 + ks * 32 + quad * 8];
        #pragma unroll
        for (int t = 0; t < 8; ++t) {
            bf16x8 b = *(const bf16x8*)&B[(t * 16 + l15) * 128 + ks * 32 + quad * 8];
            acc[t] = __builtin_amdgcn_mfma_f32_16x16x32_bf16(a, b, acc[t], 0, 0, 0);
        }
    }
    #pragma unroll
    for (int reg = 0; reg < 4; ++reg) {
        int row = row0 + w * 16 + quad * 4 + reg;
        if (row >= NN) continue;
        #pragma unroll
        for (int t = 0; t < 8; ++t) {
            int col = t * 16 + l15;
            float v = acc[t][reg];
            if (gy == 0)      sbf[row * 256 + col]       = f2bf(v);
            else if (gy == 1) sbf[row * 256 + 128 + col] = f2bf(v);
            else if (gy == 2) hbf[row * 256 + col]       = f2bf(gelu_f(v + pool_b[col]));
            else              hbf[row * 256 + 128 + col] = f2bf(gelu_f(v + pool2_b[col]));
        }
    }
}

// ---------------- edge GEMM (bf16 MFMA, dst-sorted) + fused epilogue -> sev ----------------
__global__ __launch_bounds__(256) void gemm_edge(const unsigned short* __restrict__ featbf,
                                                 const unsigned short* __restrict__ wamulbf,
                                                 const unsigned short* __restrict__ sbf,
                                                 float* __restrict__ ws) {
    __shared__ unsigned short As[64 * 136];
    __shared__ unsigned short Sbf[64 * 136];
    __shared__ int sI[64], dI[64];
    __shared__ float waout_s[128], be_s[128];
    int tid = threadIdx.x;
    int e0 = blockIdx.x * 64;
    const int2* ssrcd = (const int2*)(ws + OFF_SSRCD);
    if (tid < 64) { int2 v = ssrcd[e0 + tid]; sI[tid] = v.x; dI[tid] = v.y; }
    else if (tid < 192) { int i = tid - 64; waout_s[i] = ws[OFF_WAOUT + i]; be_s[i] = ws[OFF_BE + i]; }
    float b_aout = ws[OFF_BAOUT];
    float* e_out = ws + OFF_SEV;
    __syncthreads();

    #pragma unroll
    for (int it = 0; it < 4; ++it) {
        int idx = tid + it * 256;
        int r = idx >> 4, u = idx & 15;
        int s = sI[r], d = dI[r];
        uint4 av = *(const uint4*)&featbf[s * 128 + u * 8];
        uint4 bv = *(const uint4*)&featbf[d * 128 + u * 8];
        uint4 m;
        m.x = mulpack(av.x, bv.x); m.y = mulpack(av.y, bv.y);
        m.z = mulpack(av.z, bv.z); m.w = mulpack(av.w, bv.w);
        *(uint4*)&As[r * 136 + u * 8] = m;
        uint4 s1 = *(const uint4*)&sbf[s * 256 + u * 8];
        uint4 s2 = *(const uint4*)&sbf[d * 256 + 128 + u * 8];
        uint4 sm;
        sm.x = addpack(s1.x, s2.x); sm.y = addpack(s1.y, s2.y);
        sm.z = addpack(s1.z, s2.z); sm.w = addpack(s1.w, s2.w);
        *(uint4*)&Sbf[r * 136 + u * 8] = sm;
    }
    __syncthreads();

    int lane = tid & 63, w = tid >> 6;
    int quad = lane >> 4, l15 = lane & 15;
    f32x4 acc[8] = {};
    #pragma unroll 1
    for (int ks = 0; ks < 4; ++ks) {
        bf16x8 a = *(const bf16x8*)&As[(w * 16 + l15) * 136 + ks * 32 + quad * 8];
        #pragma unroll
        for (int t = 0; t < 8; ++t) {
            bf16x8 b = *(const bf16x8*)&wamulbf[(t * 16 + l15) * 128 + ks * 32 + quad * 8];
            acc[t] = __builtin_amdgcn_mfma_f32_16x16x32_bf16(a, b, acc[t], 0, 0, 0);
        }
    }

    #pragma unroll
    for (int reg = 0; reg < 4; ++reg) {
        int r = w * 16 + quad * 4 + reg;
        float partial = 0.0f;
        #pragma unroll
        for (int t = 0; t < 8; ++t) {
            int col = t * 16 + l15;
            float v = acc[t][reg] + bf2f(Sbf[r * 136 + col]) + be_s[col];
            partial += gelu_f(v) * waout_s[col];
        }
        partial += __shfl_xor(partial, 1, 16);
        partial += __shfl_xor(partial, 2, 16);
        partial += __shfl_xor(partial, 4, 16);
        partial += __shfl_xor(partial, 8, 16);
        if (l15 == 0) e_out[e0 + r] = leaky_f(partial + b_aout);
    }
}

// ---------------- final GEMM (MFMA, K=384, single-stage LDS) -> out f32 ----------------
__global__ __launch_bounds__(256) void gemm_final_mfma(const unsigned short* __restrict__ neighbf,
                                                       const unsigned short* __restrict__ featbf,
                                                       const unsigned short* __restrict__ wfinbf,
                                                       float* __restrict__ out,
                                                       const float* __restrict__ ws) {
    __shared__ unsigned short As[64 * 392];   // 64 rows x 384 cols bf16 (+8 pad)
    __shared__ float bfin_s[128];
    int tid = threadIdx.x;
    int row0 = blockIdx.x * 64;
    if (tid < 128) bfin_s[tid] = ws[OFF_BFIN + tid];
    #pragma unroll
    for (int rg = 0; rg < 3; ++rg) {
        #pragma unroll
        for (int it = 0; it < 4; ++it) {
            int idx = tid + it * 256;
            int r = idx >> 4, u = idx & 15;
            int rr = min(row0 + r, NN - 1);
            const unsigned short* sp = (rg == 0) ? &neighbf[rr * 256 + u * 8]
                                     : (rg == 1) ? &neighbf[rr * 256 + 128 + u * 8]
                                                 : &featbf[rr * 128 + u * 8];
            *(uint4*)&As[r * 392 + rg * 128 + u * 8] = *(const uint4*)sp;
        }
    }
    __syncthreads();
    int lane = tid & 63, w = tid >> 6;
    int quad = lane >> 4, l15 = lane & 15;
    f32x4 acc[8] = {};
    #pragma unroll 1
    for (int ks = 0; ks < 12; ++ks) {
        bf16x8 a = *(const bf16x8*)&As[(w * 16 + l15) * 392 + ks * 32 + quad * 8];
        #pragma unroll
        for (int t = 0; t < 8; ++t) {
            bf16x8 b = *(const bf16x8*)&wfinbf[(t * 16 + l15) * 384 + ks * 32 + quad * 8];
            acc[t] = __builtin_amdgcn_mfma_f32_16x16x32_bf16(a, b, acc[t], 0, 0, 0);
        }
    }
    #pragma unroll
    for (int reg = 0; reg < 4; ++reg) {
        int row = row0 + w * 16 + quad * 4 + reg;
        if (row >= NN) continue;
        #pragma unroll
        for (int t = 0; t < 8; ++t) {
            int col = t * 16 + l15;
            out[row * 128 + col] = acc[t][reg] + bfin_s[col];
        }
    }
}

// ---------------- MLP layer (MFMA, in-place on out; block reads only its own rows) ----------------
__global__ __launch_bounds__(256) void gemm_mlp_mfma(float* __restrict__ out,
                                                     const unsigned short* __restrict__ wmlp,
                                                     const float* __restrict__ bias) {
    __shared__ unsigned short As[64 * 136];
    int tid = threadIdx.x;
    int row0 = blockIdx.x * 64;
    #pragma unroll
    for (int it = 0; it < 8; ++it) {
        int idx = tid + it * 256;            // 64 rows x 32 float4-units
        int r = idx >> 5, u = idx & 31;
        int rr = min(row0 + r, NN - 1);      // clamp stays within this block's rows
        float4 v = ((const float4*)out)[rr * 32 + u];
        unsigned p0 = pk_bf16(gelu_f(v.x), gelu_f(v.y));
        unsigned p1 = pk_bf16(gelu_f(v.z), gelu_f(v.w));
        *(unsigned*)&As[r * 136 + u * 4]     = p0;
        *(unsigned*)&As[r * 136 + u * 4 + 2] = p1;
    }
    __syncthreads();
    int lane = tid & 63, w = tid >> 6;
    int quad = lane >> 4, l15 = lane & 15;
    f32x4 acc[8] = {};
    #pragma unroll 1
    for (int ks = 0; ks < 4; ++ks) {
        bf16x8 a = *(const bf16x8*)&As[(w * 16 + l15) * 136 + ks * 32 + quad * 8];
        #pragma unroll
        for (int t = 0; t < 8; ++t) {
            bf16x8 b = *(const bf16x8*)&wmlp[(t * 16 + l15) * 128 + ks * 32 + quad * 8];
            acc[t] = __builtin_amdgcn_mfma_f32_16x16x32_bf16(a, b, acc[t], 0, 0, 0);
        }
    }
    #pragma unroll
    for (int reg = 0; reg < 4; ++reg) {
        int row = row0 + w * 16 + quad * 4 + reg;
        if (row >= NN) continue;
        #pragma unroll
        for (int t = 0; t < 8; ++t) {
            int col = t * 16 + l15;
            out[row * 128 + col] += acc[t][reg] + bias[col];
        }
    }
}

// ---------------- host launch ----------------
extern "C" void kernel_launch(void* const* d_in, const int* in_sizes, int n_in,
                              void* d_out, int out_size, void* d_ws, size_t ws_size,
                              hipStream_t stream) {
    const float* feat = (const float*)d_in[0];
    WnormArgs wa;
    wa.asrc_v = (const float*)d_in[1];  wa.asrc_g = (const float*)d_in[2];  wa.asrc_b = (const float*)d_in[3];
    wa.adst_v = (const float*)d_in[4];  wa.adst_g = (const float*)d_in[5];  wa.adst_b = (const float*)d_in[6];
    wa.asub_v = (const float*)d_in[7];  wa.asub_g = (const float*)d_in[8];  wa.asub_b = (const float*)d_in[9];
    wa.amul_v = (const float*)d_in[10]; wa.amul_g = (const float*)d_in[11]; wa.amul_b = (const float*)d_in[12];
    wa.aout_v = (const float*)d_in[13]; wa.aout_g = (const float*)d_in[14]; wa.aout_b = (const float*)d_in[15];
    wa.pool_v = (const float*)d_in[16]; wa.pool_g = (const float*)d_in[17]; wa.pool_b = (const float*)d_in[18];
    wa.pool2_v= (const float*)d_in[19]; wa.pool2_g= (const float*)d_in[20]; wa.pool2_b= (const float*)d_in[21];
    wa.self_v = (const float*)d_in[22]; wa.self_g = (const float*)d_in[23]; wa.self_b = (const float*)d_in[24];
    wa.neigh_v= (const float*)d_in[25]; wa.neigh_g= (const float*)d_in[26]; wa.neigh_b= (const float*)d_in[27];
    wa.neigh2_v=(const float*)d_in[28]; wa.neigh2_g=(const float*)d_in[29]; wa.neigh2_b=(const float*)d_in[30];
    wa.mlp_v  = (const float*)d_in[31]; wa.mlp_g  = (const float*)d_in[32]; wa.mlp_b  = (const float*)d_in[33];
    const int* src = (const int*)d_in[34];
    const int* dst = (const int*)d_in[35];
    float* out = (float*)d_out;
    float* ws = (float*)d_ws;
    wa.ws = ws;
    unsigned short* featbf  = (unsigned short*)(ws + OFF_FEATBF);
    unsigned short* sbf     = (unsigned short*)(ws + OFF_SBF);
    unsigned short* hbf     = (unsigned short*)(ws + OFF_HBF);
    unsigned short* neighbf = (unsigned short*)(ws + OFF_NEIGHBF);
    unsigned short* wnodebf = (unsigned short*)(ws + OFF_WNODEBF);
    unsigned short* wfinbf  = (unsigned short*)(ws + OFF_WFINBF);
    unsigned short* wmlpbf  = (unsigned short*)(ws + OFF_WMLPBF);
    unsigned short* wamulbf = (unsigned short*)(ws + OFF_WAMULBF);

    // 1) normalized weights + fused bias vectors
    wnorm_kernel<<<dim3(1281), dim3(128), 0, stream>>>(wa);
    // 2) bf16 conversions
    convert_feat_kernel<<<dim3(NN * 128 / (256 * 8)), dim3(256), 0, stream>>>(feat, featbf);
    convert_weights_kernel<<<dim3(640), dim3(256), 0, stream>>>(ws);
    // 3) CSR-by-dst
    hist_zero_kernel<<<dim3((NN + 255) / 256), dim3(256), 0, stream>>>(ws);
    hist_kernel<<<dim3((EE + 255) / 256), dim3(256), 0, stream>>>(dst, ws);
    scan_kernel<<<dim3(1), dim3(1024), 0, stream>>>(ws);
    scatteridx_kernel<<<dim3((EE + 255) / 256), dim3(256), 0, stream>>>(src, dst, ws);
    // 4) node-level GEMM (MFMA): S table + h/h2 (all bf16)
    gemm_node_mfma<<<dim3(782, 4), dim3(256), 0, stream>>>(featbf, wa.pool_b, wa.pool2_b, sbf, hbf, wnodebf);
    // 5) edge GEMM (MFMA, dst-sorted) -> sev
    gemm_edge<<<dim3(EE / 64), dim3(256), 0, stream>>>(featbf, wamulbf, sbf, ws);
    // 6) segmented reduce -> neighbf (max zeroed | mean)
    segreduce_kernel<<<dim3(NN / 4), dim3(256), 0, stream>>>(ws);
    // 7) final GEMM (MFMA) -> out f32
    gemm_final_mfma<<<dim3(782), dim3(256), 0, stream>>>(neighbf, featbf, wfinbf, out, ws);
    // 8) two residual MLP layers (MFMA, in-place, block-self-contained rows)
    gemm_mlp_mfma<<<dim3(782), dim3(256), 0, stream>>>(out, wmlpbf, wa.mlp_b);
    gemm_mlp_mfma<<<dim3(782), dim3(256), 0, stream>>>(out, wmlpbf + 16384, wa.mlp_b + 128);
}